// Round 9
// baseline (489.910 us; speedup 1.0000x reference)
//
#include <hip/hip_runtime.h>
#include <stdint.h>

typedef unsigned short ushort_t;

#define B8  8
#define D6  6
#define NC  48
#define HH  256
#define WW  256
#define HWp 65536
#define H2  128
#define HW2 16384

__device__ __constant__ int c_T0[8] = {0,1,1,1,0,-1,-1,-1};
__device__ __constant__ int c_T1[8] = {1,1,0,-1,-1,-1,0,1};

__device__ inline float bf2f(ushort_t u){ union{unsigned int i; float f;} w; w.i = ((unsigned int)u)<<16; return w.f; }
__device__ inline ushort_t f2bf(float f){ union{float f; unsigned int i;} w; w.f=f; unsigned int xx=w.i;
  return (ushort_t)((xx + 0x7fffu + ((xx>>16)&1u)) >> 16); }
__device__ inline float tanhf_(float x){ float e=__expf(2.f*x); return 1.f - 2.f/(e+1.f); }
__device__ inline float sigm_(float x){ return 1.f/(1.f+__expf(-x)); }
__device__ inline float ldg_(const void* p, size_t i, int isbf){
  return isbf ? bf2f(((const ushort_t*)p)[i]) : ((const float*)p)[i];
}

typedef short short8 __attribute__((ext_vector_type(8)));
typedef float f4 __attribute__((ext_vector_type(4)));
typedef ushort_t us4 __attribute__((ext_vector_type(4)));
typedef ushort_t us8 __attribute__((ext_vector_type(8)));
union AB { short8 s; us4 h[2]; us8 u; };

// ---------------- dtype detection ----------------
__global__ __launch_bounds__(256) void k_detect(const ushort_t* x, float* flag){
  int t=threadIdx.x; int cnt=0;
  for(int i=t;i<4096;i+=256){
    ushort_t u=x[2*i];
    int e=(u>>7)&0xff;
    if(e>=100 && e<=150) cnt++;
  }
  for(int o=32;o;o>>=1) cnt+=__shfl_down(cnt,o,64);
  __shared__ int sh4[4];
  if((t&63)==0) sh4[t>>6]=cnt;
  __syncthreads();
  if(t==0){ int tot=sh4[0]+sh4[1]+sh4[2]+sh4[3]; flag[0] = (tot>=2048)?1.f:0.f; }
}

// ---------------- weight conversion to fp32 ----------------
struct WC { const ushort_t* src[10]; int off[10]; int n[10]; };

__global__ __launch_bounds__(256) void k_wcvt(WC wc, float* dst, const float* dfl){
  int isbf = dfl[0]>0.5f;
  int t = blockIdx.y; int n = wc.n[t]; const ushort_t* s = wc.src[t]; float* d = dst + wc.off[t];
  for(int i = blockIdx.x*256 + threadIdx.x; i < n; i += gridDim.x*256)
    d[i] = isbf ? bf2f(s[i]) : ((const float*)s)[i];
}

// ---------------- MFMA weight prep ----------------
__global__ __launch_bounds__(256) void k_wprep(const float* w2src, const float* w1src,
                                               ushort_t* wb2, ushort_t* wb1){
  int t = blockIdx.x*256+threadIdx.x;
  if(t<3456){
    int lane=t&63; int rest=t>>6;
    int ks=rest&1; int g=rest>>1; int tap=g%9; int nt=g/9;
    int oc=nt*16+(lane&15); int icb=ks*32+((lane>>4)*8);
    #pragma unroll
    for(int j=0;j<8;j++){
      int ic=icb+j;
      float v = (ic<48) ? w2src[(oc*48+ic)*9+tap] : 0.f;
      wb2[(size_t)t*8+j]=f2bf(v);
    }
  } else if(t<5184){
    int tt=t-3456; int lane=tt&63; int g=tt>>6; int tap=g%9; int nt=g/9;
    int oc=nt*16+(lane&15); int icb=(lane>>4)*8;
    #pragma unroll
    for(int j=0;j<8;j++){
      int ic=icb+j;
      float v = (ic<10) ? w1src[(oc*10+ic)*9+tap] : 0.f;
      wb1[(size_t)tt*8+j]=f2bf(v);
    }
  }
}

// ---------------- 6-channel moment reduction ----------------
__global__ __launch_bounds__(256) void k_mom(const void* src, const float* dfl, int isbfc,
                                             int sh, int npix, float* out){
  int isbf = dfl ? (dfl[0]>0.5f) : isbfc;
  float vals[27];
  #pragma unroll
  for(int i=0;i<27;i++) vals[i]=0.f;
  int stride = gridDim.x*256;
  int msk = (1<<sh)-1;
  for(int p = blockIdx.x*256+threadIdx.x; p < npix; p += stride){
    int b = p >> sh; int hw = p & msk;
    float v[6];
    #pragma unroll
    for(int d=0; d<6; d++){
      size_t idx = (((size_t)(b*6+d))<<sh) + hw;
      v[d] = ldg_(src, idx, isbf);
    }
    int q=6;
    #pragma unroll
    for(int d=0;d<6;d++){
      vals[d]+=v[d];
      #pragma unroll
      for(int e=d;e<6;e++){ vals[q] += v[d]*v[e]; q++; }
    }
  }
  __shared__ float red[4][27];
  int wid=threadIdx.x>>6, lane=threadIdx.x&63;
  #pragma unroll
  for(int i=0;i<27;i++){
    float v=vals[i];
    for(int o=32;o;o>>=1) v+=__shfl_down(v,o,64);
    if(lane==0) red[wid][i]=v;
  }
  __syncthreads();
  if(threadIdx.x<27)
    atomicAdd(&out[threadIdx.x],
      red[0][threadIdx.x]+red[1][threadIdx.x]+red[2][threadIdx.x]+red[3][threadIdx.x]);
}

__global__ __launch_bounds__(64) void k_msb(const float* mom, const float* W1,
      const void* g, const void* b, const float* dfl, float invN, float* scale, float* bias){
  int c = threadIdx.x; if(c>=NC) return;
  int isbf = dfl[0]>0.5f;
  const int st[6]={0,6,11,15,18,20};
  float wr[6];
  #pragma unroll
  for(int d=0;d<6;d++) wr[d]=W1[c*6+d];
  float mean=0.f;
  #pragma unroll
  for(int d=0;d<6;d++) mean += wr[d]*mom[d];
  mean *= invN;
  float e2=0.f;
  #pragma unroll
  for(int d=0;d<6;d++){
    #pragma unroll
    for(int e=d;e<6;e++){
      float mm = mom[6 + st[d] + (e-d)];
      e2 += wr[d]*wr[e]*((e==d)?1.f:2.f)*mm;
    }
  }
  e2 *= invN;
  float var = e2 - mean*mean;
  float sc = ldg_(g,c,isbf) * rsqrtf(var + 1e-5f);
  scale[c]=sc; bias[c]= ldg_(b,c,isbf) - sc*mean;
}

// ---------------- compenv ----------------
__global__ __launch_bounds__(256) void k_env(const void* x, const float* dfl,
      const float* w1, const float* w2, const float* sc, const float* bi, float* e){
  int isbf = dfl[0]>0.5f;
  int p = blockIdx.x*256+threadIdx.x;
  int b = p >> 16; int hw = p & 65535;
  float v[6];
  #pragma unroll
  for(int d=0; d<6; d++) v[d]=ldg_(x,(size_t)(b*6+d)*HWp + hw, isbf);
  float acc=0.f;
  for(int c=0;c<NC;c++){
    float y=0.f;
    #pragma unroll
    for(int d=0;d<6;d++) y += w1[c*6+d]*v[d];
    acc += w2[c]*tanhf_(sc[c]*y + bi[c]);
  }
  e[(size_t)b*HWp + hw]=acc;
}

// ---------------- h1 (MFMA) -> channels-last bf16 [8][258][258][48] ----------------
__global__ __launch_bounds__(256) void k_h1m(const void* x, const float* dfl, const float* e,
      const ushort_t* wb1, ushort_t* h1cl){
  __shared__ __attribute__((aligned(16))) ushort_t tile[324*24];  // [pix 18x18][icdim 24]
  int isbf = dfl[0]>0.5f;
  int b = blockIdx.y;
  int ti = blockIdx.x/17, tj = blockIdx.x%17;
  int i0 = ti*16, j0 = tj*16;
  {
    us8 z;
    #pragma unroll
    for(int j=0;j<8;j++) z[j]=0;
    us8* tp=(us8*)tile;
    for(int idx=threadIdx.x; idx<972; idx+=256) tp[idx]=z;
  }
  __syncthreads();
  for(int idx=threadIdx.x; idx<3240; idx+=256){
    int pix = idx/10, ic = idx-pix*10;
    int r = pix/18, c = pix-r*18;
    int gy = i0-2+r, gx = j0-2+c;
    float v = 0.f;
    if(gy>=0 && gy<HH && gx>=0 && gx<WW){
      if(ic<2) v = ldg_(x, ((size_t)(b*6+ic)*HH + gy)*WW + gx, isbf);
      else { int k=ic-2;
        int yy=(gy + c_T1[k]) & 255; int xx=(gx - c_T0[k]) & 255;
        v = e[((size_t)b*HH + yy)*WW + xx]; }
    }
    tile[pix*24+ic]=f2bf(v);
  }
  __syncthreads();
  int lane = threadIdx.x&63, w = threadIdx.x>>6;
  int n = lane&15, quad = lane>>4;
  int qoff = (quad<2) ? quad*8 : 16;   // quads 2,3 -> zero slots (B=0 there)
  f4 acc[4][3];
  #pragma unroll
  for(int a=0;a<4;a++)
    #pragma unroll
    for(int c=0;c<3;c++) acc[a][c]=(f4){0.f,0.f,0.f,0.f};
  #pragma unroll
  for(int tap=0; tap<9; tap++){
    int ki=tap/3, kj=tap%3;
    AB Bf[3];
    #pragma unroll
    for(int nt=0;nt<3;nt++) Bf[nt].u = *(const us8*)&wb1[((size_t)((nt*9+tap)*64+lane))*8];
    #pragma unroll
    for(int yy=0; yy<4; yy++){
      int y = w*4 + yy;
      AB a; a.u = *(const us8*)&tile[((y+ki)*18 + n + kj)*24 + qoff];
      #pragma unroll
      for(int nt=0;nt<3;nt++)
        acc[yy][nt] = __builtin_amdgcn_mfma_f32_16x16x32_bf16(a.s, Bf[nt].s, acc[yy][nt], 0,0,0);
    }
  }
  #pragma unroll
  for(int yy=0;yy<4;yy++){
    int Y = i0 + w*4 + yy;
    if(Y>=258) continue;
    #pragma unroll
    for(int nt=0;nt<3;nt++){
      int oc = nt*16 + n;
      #pragma unroll
      for(int r=0;r<4;r++){
        int X = j0 + quad*4 + r;
        if(X<258)
          h1cl[(((size_t)b*258 + Y)*258 + X)*48 + oc] = f2bf(tanhf_(acc[yy][nt][r]));
      }
    }
  }
}

// ---------------- h2 (MFMA) -> planar bf16 [8][48][256][256], fused BN stats ----------------
// BARRIER-FREE: each wave stages its own 6x18 pixel region (10.4KB) via async
// global_load_lds, waits only on its own vmcnt(0), computes. Waves slide freely.
__global__ __launch_bounds__(256,3) void k_h2m(const ushort_t* h1cl, const ushort_t* wb2,
      ushort_t* h2h, float* stats){
  __shared__ __attribute__((aligned(16))) ushort_t tile[20800];  // 4 waves x 5200 ushorts
  __shared__ float red[4][3][16][2];
  int b = blockIdx.y;
  int ti = blockIdx.x>>4, tj = blockIdx.x&15;
  int i0 = ti*16, j0 = tj*16;
  int lane = threadIdx.x&63, w = threadIdx.x>>6;
  ushort_t* wtile = &tile[w*5200];
  int r0 = i0 + w*4;
  // private async staging: 11 rounds, chunks 0..647 (6 rows x 18 cols x 6 16B-chunks)
  #pragma unroll
  for(int it=0; it<11; it++){
    int chunk = it*64 + lane;
    if(chunk < 648){
      int cpix = chunk/6, cq = chunk - cpix*6;
      int rr = cpix/18, cc = cpix - rr*18;
      const ushort_t* src = &h1cl[(((size_t)b*258 + r0+rr)*258 + (j0+cc))*48 + cq*8];
      __builtin_amdgcn_global_load_lds(
          (const __attribute__((address_space(1))) unsigned int*)src,
          (__attribute__((address_space(3))) unsigned int*)(wtile + it*512),
          16, 0, 0);
    }
  }
  if(lane<16) wtile[5184+lane]=0;        // per-wave 32B zero tail (dead-K reads)
  __builtin_amdgcn_s_waitcnt(0x0F70);    // vmcnt(0): own staging complete
  int n = lane&15, quad = lane>>4;
  f4 acc[4][3];
  #pragma unroll
  for(int a=0;a<4;a++)
    #pragma unroll
    for(int c=0;c<3;c++) acc[a][c]=(f4){0.f,0.f,0.f,0.f};
  #pragma unroll
  for(int tap=0; tap<9; tap++){
    int ki=tap/3, kj=tap%3;
    AB Bf[3][2];
    #pragma unroll
    for(int nt=0;nt<3;nt++)
      #pragma unroll
      for(int ks=0;ks<2;ks++)
        Bf[nt][ks].u = *(const us8*)&wb2[((size_t)(((nt*9+tap)*2+ks)*64+lane))*8];
    #pragma unroll
    for(int yy=0; yy<4; yy++){
      int pix = (yy+ki)*18 + n + kj;
      AB a0, a1;
      a0.u = *(const us8*)(wtile + pix*48 + quad*8);
      a1.u = (quad<2) ? *(const us8*)(wtile + pix*48 + 32 + quad*8)
                      : *(const us8*)(wtile + 5184);
      #pragma unroll
      for(int nt=0;nt<3;nt++){
        acc[yy][nt] = __builtin_amdgcn_mfma_f32_16x16x32_bf16(a0.s, Bf[nt][0].s, acc[yy][nt], 0,0,0);
        acc[yy][nt] = __builtin_amdgcn_mfma_f32_16x16x32_bf16(a1.s, Bf[nt][1].s, acc[yy][nt], 0,0,0);
      }
    }
  }
  float s[3]={0.f,0.f,0.f}, q[3]={0.f,0.f,0.f};
  #pragma unroll
  for(int yy=0;yy<4;yy++){
    int Y = r0 + yy;
    #pragma unroll
    for(int nt=0;nt<3;nt++){
      int oc = nt*16 + n;
      size_t base = ((size_t)(b*NC+oc)*HH + Y)*WW + j0 + quad*4;
      us4 u;
      #pragma unroll
      for(int r=0;r<4;r++){
        float v=tanhf_(acc[yy][nt][r]);
        u[r]=f2bf(v);
        float vb=bf2f(u[r]);
        s[nt]+=vb; q[nt]+=vb*vb;
      }
      *(us4*)&h2h[base] = u;
    }
  }
  #pragma unroll
  for(int nt=0;nt<3;nt++){
    s[nt]+=__shfl_xor(s[nt],16,64); s[nt]+=__shfl_xor(s[nt],32,64);
    q[nt]+=__shfl_xor(q[nt],16,64); q[nt]+=__shfl_xor(q[nt],32,64);
  }
  if(quad==0){
    #pragma unroll
    for(int nt=0;nt<3;nt++){ red[w][nt][n][0]=s[nt]; red[w][nt][n][1]=q[nt]; }
  }
  __syncthreads();
  if(threadIdx.x<48){
    int oc=threadIdx.x; int nt=oc>>4, nn=oc&15;
    float S=red[0][nt][nn][0]+red[1][nt][nn][0]+red[2][nt][nn][0]+red[3][nt][nn][0];
    float Q=red[0][nt][nn][1]+red[1][nt][nn][1]+red[2][nt][nn][1]+red[3][nt][nn][1];
    atomicAdd(&stats[2*oc],S); atomicAdd(&stats[2*oc+1],Q);
  }
}

// ---------------- per-channel sum/sumsq (t1) ----------------
__global__ __launch_bounds__(256) void k_cstat(const float* srcf, const ushort_t* srch, int isbf,
      int C, int HWn, int Bn, int S, float* stats){
  int c = blockIdx.x % C; int s = blockIdx.x / C;
  float sum=0.f, sq=0.f;
  for(int b=0;b<Bn;b++){
    size_t base=((size_t)b*C+c)*HWn;
    for(int i=s*256+threadIdx.x; i<HWn; i+=S*256){
      float v = isbf ? bf2f(srch[base+i]) : srcf[base+i];
      sum+=v; sq+=v*v;
    }
  }
  for(int o=32;o;o>>=1){ sum+=__shfl_down(sum,o,64); sq+=__shfl_down(sq,o,64); }
  __shared__ float ls[4], lq[4];
  int wid=threadIdx.x>>6;
  if((threadIdx.x&63)==0){ ls[wid]=sum; lq[wid]=sq; }
  __syncthreads();
  if(threadIdx.x==0){
    atomicAdd(&stats[2*c],   ls[0]+ls[1]+ls[2]+ls[3]);
    atomicAdd(&stats[2*c+1], lq[0]+lq[1]+lq[2]+lq[3]);
  }
}

__global__ __launch_bounds__(64) void k_csb(const float* stats, const void* g, const void* b,
      const float* dfl, float invN, float* scale, float* bias){
  int c=threadIdx.x; if(c>=NC) return;
  int isbf = dfl[0]>0.5f;
  float mean=stats[2*c]*invN; float var=stats[2*c+1]*invN - mean*mean;
  float s=ldg_(g,c,isbf)*rsqrtf(var+1e-5f);
  scale[c]=s; bias[c]=ldg_(b,c,isbf)-s*mean;
}

// ---------------- CHANGE ----------------
__global__ __launch_bounds__(256) void k_change(const ushort_t* h2h,
      const float* wc2, const float* sc, const float* bi, float* CH){
  int p=blockIdx.x*256+threadIdx.x;
  int b=p>>14; int rem=p&16383; int i=rem>>7; int j=rem&127;
  float acc=0.f;
  for(int ic=0;ic<NC;ic++){
    size_t base=((size_t)(b*NC+ic)*HH + 2*i)*WW + 2*j;
    float s=sc[ic], t=bi[ic];
    #pragma unroll
    for(int ki=0;ki<2;ki++)
      #pragma unroll
      for(int kj=0;kj<2;kj++){
        float v= bf2f(h2h[base+(size_t)ki*WW+kj]);
        acc += tanhf_(s*v+t)*wc2[ic*4+ki*2+kj];
      }
  }
  CH[p]=sigm_(acc);
}

// ---------------- t1 ----------------
__global__ __launch_bounds__(256) void k_cm1(const void* x, const float* dfl, const float* w, float* t1){
  int isbf = dfl[0]>0.5f;
  int p=blockIdx.x*256+threadIdx.x;
  int b=p>>14; int rem=p&16383; int i=rem>>7; int j=rem&127;
  float v[6][2][2];
  #pragma unroll
  for(int d=0;d<6;d++)
    #pragma unroll
    for(int ki=0;ki<2;ki++)
      #pragma unroll
      for(int kj=0;kj<2;kj++)
        v[d][ki][kj]=ldg_(x, ((size_t)(b*6+d)*HH + 2*i+ki)*WW + 2*j+kj, isbf);
  for(int oc=0;oc<NC;oc++){
    int g=oc>>4;
    float a=0.f;
    #pragma unroll
    for(int icl=0;icl<2;icl++)
      #pragma unroll
      for(int ki=0;ki<2;ki++)
        #pragma unroll
        for(int kj=0;kj<2;kj++)
          a += v[2*g+icl][ki][kj]*w[((oc*2+icl)*2+ki)*2+kj];
    t1[((size_t)(b*NC+oc)*HW2) + rem]=a;
  }
}

// ---------------- t2: 16x16 tiles, group in z ----------------
__global__ __launch_bounds__(256) void k_cm2(const float* t1, const float* sc, const float* bi,
        const float* wct, float* t2){
  __shared__ float as[16][20][21];
  int b=blockIdx.y, g=blockIdx.z;
  int ti=blockIdx.x/9, tj=blockIdx.x%9;
  int i0=ti*16, j0=tj*16;
  int ty=threadIdx.x>>4, tx=threadIdx.x&15;
  for(int idx=threadIdx.x; idx<6400; idx+=256){
    int i=idx/400; int rem=idx-i*400; int r=rem/20; int cc=rem-r*20;
    int cg=g*16+i;
    int y=i0-2+r, xx=j0-2+cc;
    float v=0.f;
    if(y>=0 && y<H2 && xx>=0 && xx<H2)
      v = tanhf_(sc[cg]*t1[((size_t)(b*NC+cg)*H2 + y)*H2 + xx] + bi[cg]);
    as[i][r][cc]=v;
  }
  __syncthreads();
  float acc[16];
  #pragma unroll
  for(int o=0;o<16;o++) acc[o]=0.f;
  for(int i=0;i<16;i++){
    float p[3][3];
    #pragma unroll
    for(int ki=0;ki<3;ki++)
      #pragma unroll
      for(int kj=0;kj<3;kj++) p[ki][kj]=as[i][ty+ki][tx+kj];
    #pragma unroll
    for(int o=0;o<16;o++){
      const float* wp=&wct[((size_t)(g*16+o)*16+i)*9];
      float a=0.f;
      #pragma unroll
      for(int q=0;q<9;q++) a += p[q/3][q%3]*wp[q];
      acc[o]+=a;
    }
  }
  int ii=i0+ty, jj=j0+tx;
  if(ii<130 && jj<130){
    #pragma unroll
    for(int o=0;o<16;o++)
      t2[((size_t)(b*NC+g*16+o)*130 + ii)*130 + jj]=tanhf_(acc[o]);
  }
}

// ---------------- xm: group in z ----------------
__global__ __launch_bounds__(256) void k_cm3(const float* t2, const float* w, float* xm){
  __shared__ float ts[16][18][20];
  int b=blockIdx.y, g=blockIdx.z;
  int ti=blockIdx.x>>3, tj=blockIdx.x&7;
  int i0=ti*16, j0=tj*16;
  int ty=threadIdx.x>>4, tx=threadIdx.x&15;
  for(int idx=threadIdx.x; idx<16*18*18; idx+=256){
    int i=idx/324; int rem=idx-i*324; int r=rem/18; int cc=rem-r*18;
    int cg=g*16+i;
    ts[i][r][cc]=t2[((size_t)(b*NC+cg)*130 + i0+r)*130 + j0+cc];
  }
  __syncthreads();
  float acc[2]={0.f,0.f};
  for(int icl=0;icl<16;icl++){
    float p[3][3];
    #pragma unroll
    for(int ki=0;ki<3;ki++)
      #pragma unroll
      for(int kj=0;kj<3;kj++) p[ki][kj]=ts[icl][ty+ki][tx+kj];
    #pragma unroll
    for(int ol=0;ol<2;ol++){
      int oc=2*g+ol;
      const float* wp=&w[((size_t)oc*16+icl)*9];
      float a=0.f;
      #pragma unroll
      for(int q=0;q<9;q++) a += p[q/3][q%3]*wp[q];
      acc[ol]+=a;
    }
  }
  int ii=i0+ty, jj=j0+tx;
  #pragma unroll
  for(int ol=0;ol<2;ol++)
    xm[((size_t)(b*6+2*g+ol)*H2 + ii)*H2 + jj]=tanhf_(acc[ol]);
}

// ---------------- final ----------------
__global__ __launch_bounds__(256) void k_final(const float* xm, const float* CH, const float* w1,
      const float* w2, const float* sc, const float* bi, const float* dfl, void* outp){
  int isbf = dfl[0]>0.5f;
  int p=blockIdx.x*256+threadIdx.x;
  int b=p>>14; int rem=p&16383;
  float v[6];
  #pragma unroll
  for(int d=0;d<6;d++) v[d]=xm[((size_t)(b*6+d)*HW2)+rem];
  float born[6]={0.f,0.f,0.f,0.f,0.f,0.f};
  for(int c=0;c<NC;c++){
    float y=0.f;
    #pragma unroll
    for(int d=0;d<6;d++) y+=w1[c*6+d]*v[d];
    float a=tanhf_(sc[c]*y+bi[c]);
    #pragma unroll
    for(int d=0;d<6;d++) born[d]+=w2[d*NC+c]*a;
  }
  float C=CH[p];
  #pragma unroll
  for(int d=0;d<6;d++){
    float o=v[d]*(1.f-C)+C*born[d];
    if(d<3) o=sigm_(o);
    size_t id=((size_t)(b*6+d)*HW2)+rem;
    if(isbf) ((ushort_t*)outp)[id]=f2bf(o); else ((float*)outp)[id]=o;
  }
}

extern "C" void kernel_launch(void* const* d_in, const int* in_sizes, int n_in,
                              void* d_out, int out_size, void* d_ws, size_t ws_size,
                              hipStream_t stream){
  (void)in_sizes; (void)n_in; (void)out_size; (void)ws_size;
  const ushort_t* x    = (const ushort_t*)d_in[0];
  const ushort_t* cew1 = (const ushort_t*)d_in[1];
  const void*     ceg  = d_in[2];
  const void*     ceb  = d_in[3];
  const ushort_t* cew2 = (const ushort_t*)d_in[4];
  const ushort_t* mdct = (const ushort_t*)d_in[5];
  const ushort_t* mdc1 = (const ushort_t*)d_in[6];
  const void*     mdg  = d_in[7];
  const void*     mdb  = d_in[8];
  const ushort_t* mdc2 = (const ushort_t*)d_in[9];
  const ushort_t* cmw1 = (const ushort_t*)d_in[10];
  const void*     cmg  = d_in[11];
  const void*     cmb  = d_in[12];
  const ushort_t* cmct = (const ushort_t*)d_in[13];
  const ushort_t* cmc2 = (const ushort_t*)d_in[14];
  const ushort_t* bow1 = (const ushort_t*)d_in[15];
  const void*     bog  = d_in[16];
  const void*     bob  = d_in[17];
  const ushort_t* bow2 = (const ushort_t*)d_in[18];
  float* ws = (float*)d_ws;

  const long OW_mdct=0, OW_mdc1=4320, OW_cew1=25056, OW_cew2=25344, OW_mdc2=25392,
             OW_cmw1=25584, OW_cmct=25968, OW_cmc2=32880, OW_bow1=33744, OW_bow2=34032;
  const long OFF_STATS=34320;
  const long ST_xmom=OFF_STATS+0,  ST_cesc=OFF_STATS+64,  ST_cebi=OFF_STATS+112,
             ST_h2  =OFF_STATS+160, ST_mdsc=OFF_STATS+256, ST_mdbi=OFF_STATS+304,
             ST_t1  =OFF_STATS+352, ST_cmsc=OFF_STATS+448, ST_cmbi=OFF_STATS+496,
             ST_xmm =OFF_STATS+544, ST_bosc=OFF_STATS+608, ST_bobi=OFF_STATS+656,
             ST_FLAG=OFF_STATS+960;
  const long OFF_WB2 = OFF_STATS + 1024;
  const long OFF_WB1 = OFF_WB2 + 13824;
  const long OFF_E   = OFF_WB1 + 6912;
  const long OFF_H2  = OFF_E + 524288L;        // h2 bf16 planar: 12582912 float-slots
  const long OFF_D   = OFF_H2 + 12582912L;     // h1 channels-last bf16, later t1/t2/xm/CH
  const long OFF_T1=OFF_D, OFF_T2=OFF_D+6291456L, OFF_XM=OFF_D+12781056L, OFF_CH=OFF_D+13567488L;

  ushort_t* h1cl = (ushort_t*)(ws + OFF_D);
  ushort_t* h2h  = (ushort_t*)(ws + OFF_H2);
  ushort_t* wb2  = (ushort_t*)(ws + OFF_WB2);
  ushort_t* wb1  = (ushort_t*)(ws + OFF_WB1);
  const float* dfl = ws + ST_FLAG;

  (void)hipMemsetAsync(ws + OFF_STATS, 0, 1024*sizeof(float), stream);
  hipLaunchKernelGGL(k_detect, dim3(1), 256, 0, stream, x, ws+ST_FLAG);

  WC wc;
  const ushort_t* srcs[10] = {mdct,mdc1,cew1,cew2,mdc2,cmw1,cmct,cmc2,bow1,bow2};
  const int offs[10] = {(int)OW_mdct,(int)OW_mdc1,(int)OW_cew1,(int)OW_cew2,(int)OW_mdc2,
                        (int)OW_cmw1,(int)OW_cmct,(int)OW_cmc2,(int)OW_bow1,(int)OW_bow2};
  const int cnts[10] = {4320,20736,288,48,192,384,6912,864,288,288};
  for(int i=0;i<10;i++){ wc.src[i]=srcs[i]; wc.off[i]=offs[i]; wc.n[i]=cnts[i]; }
  hipLaunchKernelGGL(k_wcvt, dim3(81,10), 256, 0, stream, wc, ws, dfl);
  hipLaunchKernelGGL(k_wprep, dim3(21), 256, 0, stream, ws+OW_mdc1, ws+OW_mdct, wb2, wb1);

  // compenv
  hipLaunchKernelGGL(k_mom, dim3(256), 256, 0, stream, (const void*)x, dfl, 0, 16, B8*HWp, ws+ST_xmom);
  hipLaunchKernelGGL(k_msb, dim3(1), 64, 0, stream, ws+ST_xmom, ws+OW_cew1, ceg, ceb, dfl,
                     1.f/(float)(B8*HWp), ws+ST_cesc, ws+ST_cebi);
  hipLaunchKernelGGL(k_env, dim3(2048), 256, 0, stream, (const void*)x, dfl, ws+OW_cew1, ws+OW_cew2,
                     ws+ST_cesc, ws+ST_cebi, ws+OFF_E);

  // md chain (MFMA, h1 channels-last, fused h2 stats)
  hipLaunchKernelGGL(k_h1m, dim3(289,8), 256, 0, stream, (const void*)x, dfl, ws+OFF_E, wb1, h1cl);
  hipLaunchKernelGGL(k_h2m, dim3(256,8), 256, 0, stream, h1cl, wb2, h2h, ws+ST_h2);
  hipLaunchKernelGGL(k_csb, dim3(1), 64, 0, stream, ws+ST_h2, mdg, mdb, dfl, 1.f/(float)(B8*HWp),
                     ws+ST_mdsc, ws+ST_mdbi);
  hipLaunchKernelGGL(k_change, dim3(512), 256, 0, stream, h2h, ws+OW_mdc2,
                     ws+ST_mdsc, ws+ST_mdbi, ws+OFF_CH);

  // cm chain (h1 region dead; t1/t2/xm/CH overlay it)
  hipLaunchKernelGGL(k_cm1, dim3(512), 256, 0, stream, (const void*)x, dfl, ws+OW_cmw1, ws+OFF_T1);
  hipLaunchKernelGGL(k_cstat, dim3(48*8), 256, 0, stream, ws+OFF_T1, (const ushort_t*)nullptr, 0,
                     NC, HW2, B8, 8, ws+ST_t1);
  hipLaunchKernelGGL(k_csb, dim3(1), 64, 0, stream, ws+ST_t1, cmg, cmb, dfl, 1.f/(float)(B8*HW2),
                     ws+ST_cmsc, ws+ST_cmbi);
  hipLaunchKernelGGL(k_cm2, dim3(81,8,3), 256, 0, stream, ws+OFF_T1, ws+ST_cmsc, ws+ST_cmbi,
                     ws+OW_cmct, ws+OFF_T2);
  hipLaunchKernelGGL(k_cm3, dim3(64,8,3), 256, 0, stream, ws+OFF_T2, ws+OW_cmc2, ws+OFF_XM);

  // born + blend
  hipLaunchKernelGGL(k_mom, dim3(128), 256, 0, stream, (const void*)(ws+OFF_XM), (const float*)nullptr, 0,
                     14, B8*HW2, ws+ST_xmm);
  hipLaunchKernelGGL(k_msb, dim3(1), 64, 0, stream, ws+ST_xmm, ws+OW_bow1, bog, bob, dfl,
                     1.f/(float)(B8*HW2), ws+ST_bosc, ws+ST_bobi);
  hipLaunchKernelGGL(k_final, dim3(512), 256, 0, stream, ws+OFF_XM, ws+OFF_CH, ws+OW_bow1,
                     ws+OW_bow2, ws+ST_bosc, ws+ST_bobi, dfl, d_out);
}

// Round 10
// 460.556 us; speedup vs baseline: 1.0637x; 1.0637x over previous
//
#include <hip/hip_runtime.h>
#include <stdint.h>

typedef unsigned short ushort_t;

#define B8  8
#define D6  6
#define NC  48
#define HH  256
#define WW  256
#define HWp 65536
#define H2  128
#define HW2 16384

__device__ __constant__ int c_T0[8] = {0,1,1,1,0,-1,-1,-1};
__device__ __constant__ int c_T1[8] = {1,1,0,-1,-1,-1,0,1};

__device__ inline float bf2f(ushort_t u){ union{unsigned int i; float f;} w; w.i = ((unsigned int)u)<<16; return w.f; }
__device__ inline ushort_t f2bf(float f){ union{float f; unsigned int i;} w; w.f=f; unsigned int xx=w.i;
  return (ushort_t)((xx + 0x7fffu + ((xx>>16)&1u)) >> 16); }
__device__ inline float tanhf_(float x){ float e=__expf(2.f*x); return 1.f - 2.f/(e+1.f); }
__device__ inline float sigm_(float x){ return 1.f/(1.f+__expf(-x)); }
__device__ inline float ldg_(const void* p, size_t i, int isbf){
  return isbf ? bf2f(((const ushort_t*)p)[i]) : ((const float*)p)[i];
}

typedef short short8 __attribute__((ext_vector_type(8)));
typedef float f4 __attribute__((ext_vector_type(4)));
typedef ushort_t us4 __attribute__((ext_vector_type(4)));
typedef ushort_t us8 __attribute__((ext_vector_type(8)));
union AB { short8 s; us4 h[2]; us8 u; };

// ---------------- dtype detection ----------------
__global__ __launch_bounds__(256) void k_detect(const ushort_t* x, float* flag){
  int t=threadIdx.x; int cnt=0;
  for(int i=t;i<4096;i+=256){
    ushort_t u=x[2*i];
    int e=(u>>7)&0xff;
    if(e>=100 && e<=150) cnt++;
  }
  for(int o=32;o;o>>=1) cnt+=__shfl_down(cnt,o,64);
  __shared__ int sh4[4];
  if((t&63)==0) sh4[t>>6]=cnt;
  __syncthreads();
  if(t==0){ int tot=sh4[0]+sh4[1]+sh4[2]+sh4[3]; flag[0] = (tot>=2048)?1.f:0.f; }
}

// ---------------- weight conversion to fp32 ----------------
struct WC { const ushort_t* src[10]; int off[10]; int n[10]; };

__global__ __launch_bounds__(256) void k_wcvt(WC wc, float* dst, const float* dfl){
  int isbf = dfl[0]>0.5f;
  int t = blockIdx.y; int n = wc.n[t]; const ushort_t* s = wc.src[t]; float* d = dst + wc.off[t];
  for(int i = blockIdx.x*256 + threadIdx.x; i < n; i += gridDim.x*256)
    d[i] = isbf ? bf2f(s[i]) : ((const float*)s)[i];
}

// ---------------- MFMA weight prep ----------------
__global__ __launch_bounds__(256) void k_wprep(const float* w2src, const float* w1src,
                                               ushort_t* wb2, ushort_t* wb1){
  int t = blockIdx.x*256+threadIdx.x;
  if(t<3456){
    int lane=t&63; int rest=t>>6;
    int ks=rest&1; int g=rest>>1; int tap=g%9; int nt=g/9;
    int oc=nt*16+(lane&15); int icb=ks*32+((lane>>4)*8);
    #pragma unroll
    for(int j=0;j<8;j++){
      int ic=icb+j;
      float v = (ic<48) ? w2src[(oc*48+ic)*9+tap] : 0.f;
      wb2[(size_t)t*8+j]=f2bf(v);
    }
  } else if(t<5184){
    int tt=t-3456; int lane=tt&63; int g=tt>>6; int tap=g%9; int nt=g/9;
    int oc=nt*16+(lane&15); int icb=(lane>>4)*8;
    #pragma unroll
    for(int j=0;j<8;j++){
      int ic=icb+j;
      float v = (ic<10) ? w1src[(oc*10+ic)*9+tap] : 0.f;
      wb1[(size_t)tt*8+j]=f2bf(v);
    }
  }
}

// ---------------- 6-channel moment reduction ----------------
__global__ __launch_bounds__(256) void k_mom(const void* src, const float* dfl, int isbfc,
                                             int sh, int npix, float* out){
  int isbf = dfl ? (dfl[0]>0.5f) : isbfc;
  float vals[27];
  #pragma unroll
  for(int i=0;i<27;i++) vals[i]=0.f;
  int stride = gridDim.x*256;
  int msk = (1<<sh)-1;
  for(int p = blockIdx.x*256+threadIdx.x; p < npix; p += stride){
    int b = p >> sh; int hw = p & msk;
    float v[6];
    #pragma unroll
    for(int d=0; d<6; d++){
      size_t idx = (((size_t)(b*6+d))<<sh) + hw;
      v[d] = ldg_(src, idx, isbf);
    }
    int q=6;
    #pragma unroll
    for(int d=0;d<6;d++){
      vals[d]+=v[d];
      #pragma unroll
      for(int e=d;e<6;e++){ vals[q] += v[d]*v[e]; q++; }
    }
  }
  __shared__ float red[4][27];
  int wid=threadIdx.x>>6, lane=threadIdx.x&63;
  #pragma unroll
  for(int i=0;i<27;i++){
    float v=vals[i];
    for(int o=32;o;o>>=1) v+=__shfl_down(v,o,64);
    if(lane==0) red[wid][i]=v;
  }
  __syncthreads();
  if(threadIdx.x<27)
    atomicAdd(&out[threadIdx.x],
      red[0][threadIdx.x]+red[1][threadIdx.x]+red[2][threadIdx.x]+red[3][threadIdx.x]);
}

__global__ __launch_bounds__(64) void k_msb(const float* mom, const float* W1,
      const void* g, const void* b, const float* dfl, float invN, float* scale, float* bias){
  int c = threadIdx.x; if(c>=NC) return;
  int isbf = dfl[0]>0.5f;
  const int st[6]={0,6,11,15,18,20};
  float wr[6];
  #pragma unroll
  for(int d=0;d<6;d++) wr[d]=W1[c*6+d];
  float mean=0.f;
  #pragma unroll
  for(int d=0;d<6;d++) mean += wr[d]*mom[d];
  mean *= invN;
  float e2=0.f;
  #pragma unroll
  for(int d=0;d<6;d++){
    #pragma unroll
    for(int e=d;e<6;e++){
      float mm = mom[6 + st[d] + (e-d)];
      e2 += wr[d]*wr[e]*((e==d)?1.f:2.f)*mm;
    }
  }
  e2 *= invN;
  float var = e2 - mean*mean;
  float sc = ldg_(g,c,isbf) * rsqrtf(var + 1e-5f);
  scale[c]=sc; bias[c]= ldg_(b,c,isbf) - sc*mean;
}

// ---------------- compenv ----------------
__global__ __launch_bounds__(256) void k_env(const void* x, const float* dfl,
      const float* w1, const float* w2, const float* sc, const float* bi, float* e){
  int isbf = dfl[0]>0.5f;
  int p = blockIdx.x*256+threadIdx.x;
  int b = p >> 16; int hw = p & 65535;
  float v[6];
  #pragma unroll
  for(int d=0; d<6; d++) v[d]=ldg_(x,(size_t)(b*6+d)*HWp + hw, isbf);
  float acc=0.f;
  for(int c=0;c<NC;c++){
    float y=0.f;
    #pragma unroll
    for(int d=0;d<6;d++) y += w1[c*6+d]*v[d];
    acc += w2[c]*tanhf_(sc[c]*y + bi[c]);
  }
  e[(size_t)b*HWp + hw]=acc;
}

// ---------------- fused md: h1 (LDS) -> h2 -> planar bf16 [8][48][256][256] + BN stats ----------------
// Per block (16x16 h2 output): stage te 20x20x[16] (ch>=10 zero), compute h1 18x18x48
// into LDS (21 M-tiles of 16 linear pixels), then h2 from LDS. h1 never touches HBM.
__global__ __launch_bounds__(256,3) void k_md(const void* x, const float* dfl, const float* e,
      const ushort_t* wb1, const ushort_t* wb2, ushort_t* h2h, float* stats){
  __shared__ __attribute__((aligned(16))) ushort_t te[6400];    // [pix 20x20][16]
  __shared__ __attribute__((aligned(16))) ushort_t h1t[18816];  // [pix 336][56], 48..55 zero
  __shared__ float red[4][3][16][2];
  int isbf = dfl[0]>0.5f;
  int b = blockIdx.y;
  int ti = blockIdx.x>>4, tj = blockIdx.x&15;
  int i0 = ti*16, j0 = tj*16;
  int lane = threadIdx.x&63, w = threadIdx.x>>6;
  int n = lane&15, quad = lane>>4;
  // phase 0: zero te (ch>=10 must be finite-zero) + h1 ch48..55 tails
  {
    us8 z;
    #pragma unroll
    for(int j=0;j<8;j++) z[j]=0;
    us8* tp=(us8*)te;
    for(int idx=threadIdx.x; idx<800; idx+=256) tp[idx]=z;
    for(int idx=threadIdx.x; idx<336; idx+=256) *(us8*)&h1t[idx*56+48]=z;
  }
  __syncthreads();
  // phase 1: stage te ch0..9 (x 2ch + rolled e 8ch)
  for(int idx=threadIdx.x; idx<4000; idx+=256){
    int pix = idx/10, ic = idx-pix*10;
    int r = pix/20, c = pix-r*20;
    int gy = i0-2+r, gx = j0-2+c;
    float v = 0.f;
    if(gy>=0 && gy<HH && gx>=0 && gx<WW){
      if(ic<2) v = ldg_(x, ((size_t)(b*6+ic)*HH + gy)*WW + gx, isbf);
      else { int k=ic-2;
        int yy=(gy + c_T1[k]) & 255; int xx=(gx - c_T0[k]) & 255;
        v = e[((size_t)b*HH + yy)*WW + xx]; }
    }
    te[pix*16+ic]=f2bf(v);
  }
  __syncthreads();
  // phase 2: h1 = tanh(conv3x3(te,pad2)) -> h1t[18x18][48], 21 m-tiles over waves
  {
    int qoff = (quad&1)*8;        // quads 2,3: B=0, any finite A
    for(int mt=w; mt<21; mt+=4){
      int p = mt*16 + n;          // linear pixel (garbage beyond 323 -> unused slots)
      int pr = p/18, pc = p-pr*18;
      f4 hacc[3];
      #pragma unroll
      for(int nt=0;nt<3;nt++) hacc[nt]=(f4){0.f,0.f,0.f,0.f};
      #pragma unroll
      for(int tap=0; tap<9; tap++){
        int ki=tap/3, kj=tap%3;
        AB a; a.u = *(const us8*)&te[((pr+ki)*20 + pc+kj)*16 + qoff];
        #pragma unroll
        for(int nt=0;nt<3;nt++){
          AB Bf; Bf.u = *(const us8*)&wb1[((size_t)((nt*9+tap)*64+lane))*8];
          hacc[nt] = __builtin_amdgcn_mfma_f32_16x16x32_bf16(a.s, Bf.s, hacc[nt], 0,0,0);
        }
      }
      int pd = mt*16 + quad*4;    // D rows: pixel = mt*16 + quad*4 + reg
      #pragma unroll
      for(int nt=0;nt<3;nt++){
        #pragma unroll
        for(int r=0;r<4;r++)
          h1t[(pd+r)*56 + nt*16 + n] = f2bf(tanhf_(hacc[nt][r]));
      }
    }
  }
  __syncthreads();
  // phase 3: h2 = tanh(conv3x3(h1t)) + stats
  f4 acc[4][3];
  #pragma unroll
  for(int a=0;a<4;a++)
    #pragma unroll
    for(int c=0;c<3;c++) acc[a][c]=(f4){0.f,0.f,0.f,0.f};
  int q1off = 32 + ((quad<2) ? quad*8 : 16);   // dead-K quads -> zeroed 48..55
  #pragma unroll
  for(int tap=0; tap<9; tap++){
    int ki=tap/3, kj=tap%3;
    AB Bf[3][2];
    #pragma unroll
    for(int nt=0;nt<3;nt++)
      #pragma unroll
      for(int ks=0;ks<2;ks++)
        Bf[nt][ks].u = *(const us8*)&wb2[((size_t)(((nt*9+tap)*2+ks)*64+lane))*8];
    #pragma unroll
    for(int yy=0; yy<4; yy++){
      int y = w*4 + yy;
      int base = ((y+ki)*18 + n + kj)*56;
      AB a0, a1;
      a0.u = *(const us8*)&h1t[base + quad*8];
      a1.u = *(const us8*)&h1t[base + q1off];
      #pragma unroll
      for(int nt=0;nt<3;nt++){
        acc[yy][nt] = __builtin_amdgcn_mfma_f32_16x16x32_bf16(a0.s, Bf[nt][0].s, acc[yy][nt], 0,0,0);
        acc[yy][nt] = __builtin_amdgcn_mfma_f32_16x16x32_bf16(a1.s, Bf[nt][1].s, acc[yy][nt], 0,0,0);
      }
    }
  }
  float s[3]={0.f,0.f,0.f}, q[3]={0.f,0.f,0.f};
  #pragma unroll
  for(int yy=0;yy<4;yy++){
    int Y = i0 + w*4 + yy;
    #pragma unroll
    for(int nt=0;nt<3;nt++){
      int oc = nt*16 + n;
      size_t base = ((size_t)(b*NC+oc)*HH + Y)*WW + j0 + quad*4;
      us4 u;
      #pragma unroll
      for(int r=0;r<4;r++){
        float v=tanhf_(acc[yy][nt][r]);
        u[r]=f2bf(v);
        float vb=bf2f(u[r]);
        s[nt]+=vb; q[nt]+=vb*vb;
      }
      *(us4*)&h2h[base] = u;
    }
  }
  #pragma unroll
  for(int nt=0;nt<3;nt++){
    s[nt]+=__shfl_xor(s[nt],16,64); s[nt]+=__shfl_xor(s[nt],32,64);
    q[nt]+=__shfl_xor(q[nt],16,64); q[nt]+=__shfl_xor(q[nt],32,64);
  }
  if(quad==0){
    #pragma unroll
    for(int nt=0;nt<3;nt++){ red[w][nt][n][0]=s[nt]; red[w][nt][n][1]=q[nt]; }
  }
  __syncthreads();
  if(threadIdx.x<48){
    int oc=threadIdx.x; int nt=oc>>4, nn=oc&15;
    float S=red[0][nt][nn][0]+red[1][nt][nn][0]+red[2][nt][nn][0]+red[3][nt][nn][0];
    float Q=red[0][nt][nn][1]+red[1][nt][nn][1]+red[2][nt][nn][1]+red[3][nt][nn][1];
    atomicAdd(&stats[2*oc],S); atomicAdd(&stats[2*oc+1],Q);
  }
}

// ---------------- per-channel sum/sumsq ----------------
__global__ __launch_bounds__(256) void k_cstat(const float* srcf, const ushort_t* srch, int isbf,
      int C, int HWn, int Bn, int S, float* stats){
  int c = blockIdx.x % C; int s = blockIdx.x / C;
  float sum=0.f, sq=0.f;
  for(int b=0;b<Bn;b++){
    size_t base=((size_t)b*C+c)*HWn;
    for(int i=s*256+threadIdx.x; i<HWn; i+=S*256){
      float v = isbf ? bf2f(srch[base+i]) : srcf[base+i];
      sum+=v; sq+=v*v;
    }
  }
  for(int o=32;o;o>>=1){ sum+=__shfl_down(sum,o,64); sq+=__shfl_down(sq,o,64); }
  __shared__ float ls[4], lq[4];
  int wid=threadIdx.x>>6;
  if((threadIdx.x&63)==0){ ls[wid]=sum; lq[wid]=sq; }
  __syncthreads();
  if(threadIdx.x==0){
    atomicAdd(&stats[2*c],   ls[0]+ls[1]+ls[2]+ls[3]);
    atomicAdd(&stats[2*c+1], lq[0]+lq[1]+lq[2]+lq[3]);
  }
}

__global__ __launch_bounds__(64) void k_csb(const float* stats, const void* g, const void* b,
      const float* dfl, float invN, float* scale, float* bias){
  int c=threadIdx.x; if(c>=NC) return;
  int isbf = dfl[0]>0.5f;
  float mean=stats[2*c]*invN; float var=stats[2*c+1]*invN - mean*mean;
  float s=ldg_(g,c,isbf)*rsqrtf(var+1e-5f);
  scale[c]=s; bias[c]=ldg_(b,c,isbf)-s*mean;
}

// ---------------- CHANGE ----------------
__global__ __launch_bounds__(256) void k_change(const ushort_t* h2h,
      const float* wc2, const float* sc, const float* bi, float* CH){
  int p=blockIdx.x*256+threadIdx.x;
  int b=p>>14; int rem=p&16383; int i=rem>>7; int j=rem&127;
  float acc=0.f;
  for(int ic=0;ic<NC;ic++){
    size_t base=((size_t)(b*NC+ic)*HH + 2*i)*WW + 2*j;
    float s=sc[ic], t=bi[ic];
    #pragma unroll
    for(int ki=0;ki<2;ki++)
      #pragma unroll
      for(int kj=0;kj<2;kj++){
        float v= bf2f(h2h[base+(size_t)ki*WW+kj]);
        acc += tanhf_(s*v+t)*wc2[ic*4+ki*2+kj];
      }
  }
  CH[p]=sigm_(acc);
}

// ---------------- t1 (bf16) ----------------
__global__ __launch_bounds__(256) void k_cm1(const void* x, const float* dfl, const float* w, ushort_t* t1){
  int isbf = dfl[0]>0.5f;
  int p=blockIdx.x*256+threadIdx.x;
  int b=p>>14; int rem=p&16383; int i=rem>>7; int j=rem&127;
  float v[6][2][2];
  #pragma unroll
  for(int d=0;d<6;d++)
    #pragma unroll
    for(int ki=0;ki<2;ki++)
      #pragma unroll
      for(int kj=0;kj<2;kj++)
        v[d][ki][kj]=ldg_(x, ((size_t)(b*6+d)*HH + 2*i+ki)*WW + 2*j+kj, isbf);
  for(int oc=0;oc<NC;oc++){
    int g=oc>>4;
    float a=0.f;
    #pragma unroll
    for(int icl=0;icl<2;icl++)
      #pragma unroll
      for(int ki=0;ki<2;ki++)
        #pragma unroll
        for(int kj=0;kj<2;kj++)
          a += v[2*g+icl][ki][kj]*w[((oc*2+icl)*2+ki)*2+kj];
    t1[((size_t)(b*NC+oc)*HW2) + rem]=f2bf(a);
  }
}

// ---------------- t2: 16x16 tiles, group in z ----------------
__global__ __launch_bounds__(256) void k_cm2(const ushort_t* t1, const float* sc, const float* bi,
        const float* wct, float* t2){
  __shared__ float as[16][20][21];
  int b=blockIdx.y, g=blockIdx.z;
  int ti=blockIdx.x/9, tj=blockIdx.x%9;
  int i0=ti*16, j0=tj*16;
  int ty=threadIdx.x>>4, tx=threadIdx.x&15;
  for(int idx=threadIdx.x; idx<6400; idx+=256){
    int i=idx/400; int rem=idx-i*400; int r=rem/20; int cc=rem-r*20;
    int cg=g*16+i;
    int y=i0-2+r, xx=j0-2+cc;
    float v=0.f;
    if(y>=0 && y<H2 && xx>=0 && xx<H2)
      v = tanhf_(sc[cg]*bf2f(t1[((size_t)(b*NC+cg)*H2 + y)*H2 + xx]) + bi[cg]);
    as[i][r][cc]=v;
  }
  __syncthreads();
  float acc[16];
  #pragma unroll
  for(int o=0;o<16;o++) acc[o]=0.f;
  for(int i=0;i<16;i++){
    float p[3][3];
    #pragma unroll
    for(int ki=0;ki<3;ki++)
      #pragma unroll
      for(int kj=0;kj<3;kj++) p[ki][kj]=as[i][ty+ki][tx+kj];
    #pragma unroll
    for(int o=0;o<16;o++){
      const float* wp=&wct[((size_t)(g*16+o)*16+i)*9];
      float a=0.f;
      #pragma unroll
      for(int q=0;q<9;q++) a += p[q/3][q%3]*wp[q];
      acc[o]+=a;
    }
  }
  int ii=i0+ty, jj=j0+tx;
  if(ii<130 && jj<130){
    #pragma unroll
    for(int o=0;o<16;o++)
      t2[((size_t)(b*NC+g*16+o)*130 + ii)*130 + jj]=tanhf_(acc[o]);
  }
}

// ---------------- xm: group in z ----------------
__global__ __launch_bounds__(256) void k_cm3(const float* t2, const float* w, float* xm){
  __shared__ float ts[16][18][20];
  int b=blockIdx.y, g=blockIdx.z;
  int ti=blockIdx.x>>3, tj=blockIdx.x&7;
  int i0=ti*16, j0=tj*16;
  int ty=threadIdx.x>>4, tx=threadIdx.x&15;
  for(int idx=threadIdx.x; idx<16*18*18; idx+=256){
    int i=idx/324; int rem=idx-i*324; int r=rem/18; int cc=rem-r*18;
    int cg=g*16+i;
    ts[i][r][cc]=t2[((size_t)(b*NC+cg)*130 + i0+r)*130 + j0+cc];
  }
  __syncthreads();
  float acc[2]={0.f,0.f};
  for(int icl=0;icl<16;icl++){
    float p[3][3];
    #pragma unroll
    for(int ki=0;ki<3;ki++)
      #pragma unroll
      for(int kj=0;kj<3;kj++) p[ki][kj]=ts[icl][ty+ki][tx+kj];
    #pragma unroll
    for(int ol=0;ol<2;ol++){
      int oc=2*g+ol;
      const float* wp=&w[((size_t)oc*16+icl)*9];
      float a=0.f;
      #pragma unroll
      for(int q=0;q<9;q++) a += p[q/3][q%3]*wp[q];
      acc[ol]+=a;
    }
  }
  int ii=i0+ty, jj=j0+tx;
  #pragma unroll
  for(int ol=0;ol<2;ol++)
    xm[((size_t)(b*6+2*g+ol)*H2 + ii)*H2 + jj]=tanhf_(acc[ol]);
}

// ---------------- final ----------------
__global__ __launch_bounds__(256) void k_final(const float* xm, const float* CH, const float* w1,
      const float* w2, const float* sc, const float* bi, const float* dfl, void* outp){
  int isbf = dfl[0]>0.5f;
  int p=blockIdx.x*256+threadIdx.x;
  int b=p>>14; int rem=p&16383;
  float v[6];
  #pragma unroll
  for(int d=0;d<6;d++) v[d]=xm[((size_t)(b*6+d)*HW2)+rem];
  float born[6]={0.f,0.f,0.f,0.f,0.f,0.f};
  for(int c=0;c<NC;c++){
    float y=0.f;
    #pragma unroll
    for(int d=0;d<6;d++) y+=w1[c*6+d]*v[d];
    float a=tanhf_(sc[c]*y+bi[c]);
    #pragma unroll
    for(int d=0;d<6;d++) born[d]+=w2[d*NC+c]*a;
  }
  float C=CH[p];
  #pragma unroll
  for(int d=0;d<6;d++){
    float o=v[d]*(1.f-C)+C*born[d];
    if(d<3) o=sigm_(o);
    size_t id=((size_t)(b*6+d)*HW2)+rem;
    if(isbf) ((ushort_t*)outp)[id]=f2bf(o); else ((float*)outp)[id]=o;
  }
}

extern "C" void kernel_launch(void* const* d_in, const int* in_sizes, int n_in,
                              void* d_out, int out_size, void* d_ws, size_t ws_size,
                              hipStream_t stream){
  (void)in_sizes; (void)n_in; (void)out_size; (void)ws_size;
  const ushort_t* x    = (const ushort_t*)d_in[0];
  const ushort_t* cew1 = (const ushort_t*)d_in[1];
  const void*     ceg  = d_in[2];
  const void*     ceb  = d_in[3];
  const ushort_t* cew2 = (const ushort_t*)d_in[4];
  const ushort_t* mdct = (const ushort_t*)d_in[5];
  const ushort_t* mdc1 = (const ushort_t*)d_in[6];
  const void*     mdg  = d_in[7];
  const void*     mdb  = d_in[8];
  const ushort_t* mdc2 = (const ushort_t*)d_in[9];
  const ushort_t* cmw1 = (const ushort_t*)d_in[10];
  const void*     cmg  = d_in[11];
  const void*     cmb  = d_in[12];
  const ushort_t* cmct = (const ushort_t*)d_in[13];
  const ushort_t* cmc2 = (const ushort_t*)d_in[14];
  const ushort_t* bow1 = (const ushort_t*)d_in[15];
  const void*     bog  = d_in[16];
  const void*     bob  = d_in[17];
  const ushort_t* bow2 = (const ushort_t*)d_in[18];
  float* ws = (float*)d_ws;

  const long OW_mdct=0, OW_mdc1=4320, OW_cew1=25056, OW_cew2=25344, OW_mdc2=25392,
             OW_cmw1=25584, OW_cmct=25968, OW_cmc2=32880, OW_bow1=33744, OW_bow2=34032;
  const long OFF_STATS=34320;
  const long ST_xmom=OFF_STATS+0,  ST_cesc=OFF_STATS+64,  ST_cebi=OFF_STATS+112,
             ST_h2  =OFF_STATS+160, ST_mdsc=OFF_STATS+256, ST_mdbi=OFF_STATS+304,
             ST_t1  =OFF_STATS+352, ST_cmsc=OFF_STATS+448, ST_cmbi=OFF_STATS+496,
             ST_xmm =OFF_STATS+544, ST_bosc=OFF_STATS+608, ST_bobi=OFF_STATS+656,
             ST_FLAG=OFF_STATS+960;
  const long OFF_WB2 = OFF_STATS + 1024;
  const long OFF_WB1 = OFF_WB2 + 13824;
  const long OFF_E   = OFF_WB1 + 6912;
  const long OFF_H2  = OFF_E + 524288L;        // h2 bf16 planar: 12582912 float-slots
  const long OFF_D   = OFF_H2 + 12582912L;     // t1/t2/xm/CH
  const long OFF_T1=OFF_D, OFF_T2=OFF_D+6291456L, OFF_XM=OFF_D+12781056L, OFF_CH=OFF_D+13567488L;

  ushort_t* h2h  = (ushort_t*)(ws + OFF_H2);
  ushort_t* t1h  = (ushort_t*)(ws + OFF_T1);
  ushort_t* wb2  = (ushort_t*)(ws + OFF_WB2);
  ushort_t* wb1  = (ushort_t*)(ws + OFF_WB1);
  const float* dfl = ws + ST_FLAG;

  (void)hipMemsetAsync(ws + OFF_STATS, 0, 1024*sizeof(float), stream);
  hipLaunchKernelGGL(k_detect, dim3(1), 256, 0, stream, x, ws+ST_FLAG);

  WC wc;
  const ushort_t* srcs[10] = {mdct,mdc1,cew1,cew2,mdc2,cmw1,cmct,cmc2,bow1,bow2};
  const int offs[10] = {(int)OW_mdct,(int)OW_mdc1,(int)OW_cew1,(int)OW_cew2,(int)OW_mdc2,
                        (int)OW_cmw1,(int)OW_cmct,(int)OW_cmc2,(int)OW_bow1,(int)OW_bow2};
  const int cnts[10] = {4320,20736,288,48,192,384,6912,864,288,288};
  for(int i=0;i<10;i++){ wc.src[i]=srcs[i]; wc.off[i]=offs[i]; wc.n[i]=cnts[i]; }
  hipLaunchKernelGGL(k_wcvt, dim3(81,10), 256, 0, stream, wc, ws, dfl);
  hipLaunchKernelGGL(k_wprep, dim3(21), 256, 0, stream, ws+OW_mdc1, ws+OW_mdct, wb2, wb1);

  // compenv
  hipLaunchKernelGGL(k_mom, dim3(256), 256, 0, stream, (const void*)x, dfl, 0, 16, B8*HWp, ws+ST_xmom);
  hipLaunchKernelGGL(k_msb, dim3(1), 64, 0, stream, ws+ST_xmom, ws+OW_cew1, ceg, ceb, dfl,
                     1.f/(float)(B8*HWp), ws+ST_cesc, ws+ST_cebi);
  hipLaunchKernelGGL(k_env, dim3(2048), 256, 0, stream, (const void*)x, dfl, ws+OW_cew1, ws+OW_cew2,
                     ws+ST_cesc, ws+ST_cebi, ws+OFF_E);

  // md chain: fused h1+h2 (h1 LDS-resident) + stats
  hipLaunchKernelGGL(k_md, dim3(256,8), 256, 0, stream, (const void*)x, dfl, ws+OFF_E,
                     wb1, wb2, h2h, ws+ST_h2);
  hipLaunchKernelGGL(k_csb, dim3(1), 64, 0, stream, ws+ST_h2, mdg, mdb, dfl, 1.f/(float)(B8*HWp),
                     ws+ST_mdsc, ws+ST_mdbi);
  hipLaunchKernelGGL(k_change, dim3(512), 256, 0, stream, h2h, ws+OW_mdc2,
                     ws+ST_mdsc, ws+ST_mdbi, ws+OFF_CH);

  // cm chain
  hipLaunchKernelGGL(k_cm1, dim3(512), 256, 0, stream, (const void*)x, dfl, ws+OW_cmw1, t1h);
  hipLaunchKernelGGL(k_cstat, dim3(48*8), 256, 0, stream, (const float*)nullptr, t1h, 1,
                     NC, HW2, B8, 8, ws+ST_t1);
  hipLaunchKernelGGL(k_csb, dim3(1), 64, 0, stream, ws+ST_t1, cmg, cmb, dfl, 1.f/(float)(B8*HW2),
                     ws+ST_cmsc, ws+ST_cmbi);
  hipLaunchKernelGGL(k_cm2, dim3(81,8,3), 256, 0, stream, t1h, ws+ST_cmsc, ws+ST_cmbi,
                     ws+OW_cmct, ws+OFF_T2);
  hipLaunchKernelGGL(k_cm3, dim3(64,8,3), 256, 0, stream, ws+OFF_T2, ws+OW_cmc2, ws+OFF_XM);

  // born + blend
  hipLaunchKernelGGL(k_mom, dim3(128), 256, 0, stream, (const void*)(ws+OFF_XM), (const float*)nullptr, 0,
                     14, B8*HW2, ws+ST_xmm);
  hipLaunchKernelGGL(k_msb, dim3(1), 64, 0, stream, ws+ST_xmm, ws+OW_bow1, bog, bob, dfl,
                     1.f/(float)(B8*HW2), ws+ST_bosc, ws+ST_bobi);
  hipLaunchKernelGGL(k_final, dim3(512), 256, 0, stream, ws+OFF_XM, ws+OFF_CH, ws+OW_bow1,
                     ws+OW_bow2, ws+ST_bosc, ws+ST_bobi, dfl, d_out);
}

// Round 11
// 448.202 us; speedup vs baseline: 1.0931x; 1.0276x over previous
//
#include <hip/hip_runtime.h>
#include <stdint.h>

typedef unsigned short ushort_t;

#define B8  8
#define D6  6
#define NC  48
#define HH  256
#define WW  256
#define HWp 65536
#define H2  128
#define HW2 16384

__device__ __constant__ int c_T0[8] = {0,1,1,1,0,-1,-1,-1};
__device__ __constant__ int c_T1[8] = {1,1,0,-1,-1,-1,0,1};

__device__ inline float bf2f(ushort_t u){ union{unsigned int i; float f;} w; w.i = ((unsigned int)u)<<16; return w.f; }
__device__ inline ushort_t f2bf(float f){ union{float f; unsigned int i;} w; w.f=f; unsigned int xx=w.i;
  return (ushort_t)((xx + 0x7fffu + ((xx>>16)&1u)) >> 16); }
__device__ inline float tanhf_(float x){ float e=__expf(2.f*x); return 1.f - 2.f/(e+1.f); }
__device__ inline float sigm_(float x){ return 1.f/(1.f+__expf(-x)); }
__device__ inline float ldg_(const void* p, size_t i, int isbf){
  return isbf ? bf2f(((const ushort_t*)p)[i]) : ((const float*)p)[i];
}

typedef short short8 __attribute__((ext_vector_type(8)));
typedef float f4 __attribute__((ext_vector_type(4)));
typedef ushort_t us4 __attribute__((ext_vector_type(4)));
typedef ushort_t us8 __attribute__((ext_vector_type(8)));
union AB { short8 s; us4 h[2]; us8 u; };

// ---------------- dtype detection ----------------
__global__ __launch_bounds__(256) void k_detect(const ushort_t* x, float* flag){
  int t=threadIdx.x; int cnt=0;
  for(int i=t;i<4096;i+=256){
    ushort_t u=x[2*i];
    int e=(u>>7)&0xff;
    if(e>=100 && e<=150) cnt++;
  }
  for(int o=32;o;o>>=1) cnt+=__shfl_down(cnt,o,64);
  __shared__ int sh4[4];
  if((t&63)==0) sh4[t>>6]=cnt;
  __syncthreads();
  if(t==0){ int tot=sh4[0]+sh4[1]+sh4[2]+sh4[3]; flag[0] = (tot>=2048)?1.f:0.f; }
}

// ---------------- weight conversion to fp32 ----------------
struct WC { const ushort_t* src[10]; int off[10]; int n[10]; };

__global__ __launch_bounds__(256) void k_wcvt(WC wc, float* dst, const float* dfl){
  int isbf = dfl[0]>0.5f;
  int t = blockIdx.y; int n = wc.n[t]; const ushort_t* s = wc.src[t]; float* d = dst + wc.off[t];
  for(int i = blockIdx.x*256 + threadIdx.x; i < n; i += gridDim.x*256)
    d[i] = isbf ? bf2f(s[i]) : ((const float*)s)[i];
}

// ---------------- MFMA weight prep ----------------
__global__ __launch_bounds__(256) void k_wprep(const float* w2src, const float* w1src,
                                               ushort_t* wb2, ushort_t* wb1){
  int t = blockIdx.x*256+threadIdx.x;
  if(t<3456){
    int lane=t&63; int rest=t>>6;
    int ks=rest&1; int g=rest>>1; int tap=g%9; int nt=g/9;
    int oc=nt*16+(lane&15); int icb=ks*32+((lane>>4)*8);
    #pragma unroll
    for(int j=0;j<8;j++){
      int ic=icb+j;
      float v = (ic<48) ? w2src[(oc*48+ic)*9+tap] : 0.f;
      wb2[(size_t)t*8+j]=f2bf(v);
    }
  } else if(t<5184){
    int tt=t-3456; int lane=tt&63; int g=tt>>6; int tap=g%9; int nt=g/9;
    int oc=nt*16+(lane&15); int icb=(lane>>4)*8;
    #pragma unroll
    for(int j=0;j<8;j++){
      int ic=icb+j;
      float v = (ic<10) ? w1src[(oc*10+ic)*9+tap] : 0.f;
      wb1[(size_t)tt*8+j]=f2bf(v);
    }
  }
}

// ---------------- 6-channel moment reduction ----------------
__global__ __launch_bounds__(256) void k_mom(const void* src, const float* dfl, int isbfc,
                                             int sh, int npix, float* out){
  int isbf = dfl ? (dfl[0]>0.5f) : isbfc;
  float vals[27];
  #pragma unroll
  for(int i=0;i<27;i++) vals[i]=0.f;
  int stride = gridDim.x*256;
  int msk = (1<<sh)-1;
  for(int p = blockIdx.x*256+threadIdx.x; p < npix; p += stride){
    int b = p >> sh; int hw = p & msk;
    float v[6];
    #pragma unroll
    for(int d=0; d<6; d++){
      size_t idx = (((size_t)(b*6+d))<<sh) + hw;
      v[d] = ldg_(src, idx, isbf);
    }
    int q=6;
    #pragma unroll
    for(int d=0;d<6;d++){
      vals[d]+=v[d];
      #pragma unroll
      for(int e=d;e<6;e++){ vals[q] += v[d]*v[e]; q++; }
    }
  }
  __shared__ float red[4][27];
  int wid=threadIdx.x>>6, lane=threadIdx.x&63;
  #pragma unroll
  for(int i=0;i<27;i++){
    float v=vals[i];
    for(int o=32;o;o>>=1) v+=__shfl_down(v,o,64);
    if(lane==0) red[wid][i]=v;
  }
  __syncthreads();
  if(threadIdx.x<27)
    atomicAdd(&out[threadIdx.x],
      red[0][threadIdx.x]+red[1][threadIdx.x]+red[2][threadIdx.x]+red[3][threadIdx.x]);
}

__global__ __launch_bounds__(64) void k_msb(const float* mom, const float* W1,
      const void* g, const void* b, const float* dfl, float invN, float* scale, float* bias){
  int c = threadIdx.x; if(c>=NC) return;
  int isbf = dfl[0]>0.5f;
  const int st[6]={0,6,11,15,18,20};
  float wr[6];
  #pragma unroll
  for(int d=0;d<6;d++) wr[d]=W1[c*6+d];
  float mean=0.f;
  #pragma unroll
  for(int d=0;d<6;d++) mean += wr[d]*mom[d];
  mean *= invN;
  float e2=0.f;
  #pragma unroll
  for(int d=0;d<6;d++){
    #pragma unroll
    for(int e=d;e<6;e++){
      float mm = mom[6 + st[d] + (e-d)];
      e2 += wr[d]*wr[e]*((e==d)?1.f:2.f)*mm;
    }
  }
  e2 *= invN;
  float var = e2 - mean*mean;
  float sc = ldg_(g,c,isbf) * rsqrtf(var + 1e-5f);
  scale[c]=sc; bias[c]= ldg_(b,c,isbf) - sc*mean;
}

// ---------------- compenv ----------------
__global__ __launch_bounds__(256) void k_env(const void* x, const float* dfl,
      const float* w1, const float* w2, const float* sc, const float* bi, float* e){
  int isbf = dfl[0]>0.5f;
  int p = blockIdx.x*256+threadIdx.x;
  int b = p >> 16; int hw = p & 65535;
  float v[6];
  #pragma unroll
  for(int d=0; d<6; d++) v[d]=ldg_(x,(size_t)(b*6+d)*HWp + hw, isbf);
  float acc=0.f;
  for(int c=0;c<NC;c++){
    float y=0.f;
    #pragma unroll
    for(int d=0;d<6;d++) y += w1[c*6+d]*v[d];
    acc += w2[c]*tanhf_(sc[c]*y + bi[c]);
  }
  e[(size_t)b*HWp + hw]=acc;
}

// ---------------- fused md: h1 (LDS) -> h2 -> TILED bf16 [tile][48][16][16] + BN stats ----------------
__global__ __launch_bounds__(256,3) void k_md(const void* x, const float* dfl, const float* e,
      const ushort_t* wb1, const ushort_t* wb2, ushort_t* h2t, float* stats){
  __shared__ __attribute__((aligned(16))) ushort_t te[6400];    // [pix 20x20][16]
  __shared__ __attribute__((aligned(16))) ushort_t h1t[19488];  // [pix 336][58], 48..55 zero
  __shared__ float red[4][3][16][2];
  int isbf = dfl[0]>0.5f;
  int b = blockIdx.y;
  int ti = blockIdx.x>>4, tj = blockIdx.x&15;
  int i0 = ti*16, j0 = tj*16;
  int lane = threadIdx.x&63, w = threadIdx.x>>6;
  int n = lane&15, quad = lane>>4;
  // phase 0: zero te (ch>=10 must be finite-zero) + h1 ch48..55 tails
  {
    us8 z;
    #pragma unroll
    for(int j=0;j<8;j++) z[j]=0;
    us8* tp=(us8*)te;
    for(int idx=threadIdx.x; idx<800; idx+=256) tp[idx]=z;
    for(int idx=threadIdx.x; idx<336; idx+=256) *(us8*)&h1t[idx*58+48]=z;
  }
  __syncthreads();
  // phase 1: stage te ch0..9 (x 2ch + rolled e 8ch)
  for(int idx=threadIdx.x; idx<4000; idx+=256){
    int pix = idx/10, ic = idx-pix*10;
    int r = pix/20, c = pix-r*20;
    int gy = i0-2+r, gx = j0-2+c;
    float v = 0.f;
    if(gy>=0 && gy<HH && gx>=0 && gx<WW){
      if(ic<2) v = ldg_(x, ((size_t)(b*6+ic)*HH + gy)*WW + gx, isbf);
      else { int k=ic-2;
        int yy=(gy + c_T1[k]) & 255; int xx=(gx - c_T0[k]) & 255;
        v = e[((size_t)b*HH + yy)*WW + xx]; }
    }
    te[pix*16+ic]=f2bf(v);
  }
  __syncthreads();
  // phase 2: h1 = tanh(conv3x3(te,pad2)) -> h1t[18x18][58], 21 m-tiles over waves
  {
    int qoff = (quad&1)*8;        // quads 2,3: B=0, any finite A
    for(int mt=w; mt<21; mt+=4){
      int p = mt*16 + n;          // linear pixel (garbage beyond 323 -> unused slots)
      int pr = p/18, pc = p-pr*18;
      f4 hacc[3];
      #pragma unroll
      for(int nt=0;nt<3;nt++) hacc[nt]=(f4){0.f,0.f,0.f,0.f};
      #pragma unroll
      for(int tap=0; tap<9; tap++){
        int ki=tap/3, kj=tap%3;
        AB a; a.u = *(const us8*)&te[((pr+ki)*20 + pc+kj)*16 + qoff];
        #pragma unroll
        for(int nt=0;nt<3;nt++){
          AB Bf; Bf.u = *(const us8*)&wb1[((size_t)((nt*9+tap)*64+lane))*8];
          hacc[nt] = __builtin_amdgcn_mfma_f32_16x16x32_bf16(a.s, Bf.s, hacc[nt], 0,0,0);
        }
      }
      int pd = mt*16 + quad*4;    // D rows: pixel = mt*16 + quad*4 + reg
      #pragma unroll
      for(int nt=0;nt<3;nt++){
        #pragma unroll
        for(int r=0;r<4;r++)
          h1t[(pd+r)*58 + nt*16 + n] = f2bf(tanhf_(hacc[nt][r]));
      }
    }
  }
  __syncthreads();
  // phase 3: h2 = tanh(conv3x3(h1t)) + stats
  f4 acc[4][3];
  #pragma unroll
  for(int a=0;a<4;a++)
    #pragma unroll
    for(int c=0;c<3;c++) acc[a][c]=(f4){0.f,0.f,0.f,0.f};
  int q1off = 32 + ((quad<2) ? quad*8 : 16);   // dead-K quads -> zeroed 48..55
  #pragma unroll
  for(int tap=0; tap<9; tap++){
    int ki=tap/3, kj=tap%3;
    AB Bf[3][2];
    #pragma unroll
    for(int nt=0;nt<3;nt++)
      #pragma unroll
      for(int ks=0;ks<2;ks++)
        Bf[nt][ks].u = *(const us8*)&wb2[((size_t)(((nt*9+tap)*2+ks)*64+lane))*8];
    #pragma unroll
    for(int yy=0; yy<4; yy++){
      int y = w*4 + yy;
      int base = ((y+ki)*18 + n + kj)*58;
      AB a0, a1;
      a0.u = *(const us8*)&h1t[base + quad*8];
      a1.u = *(const us8*)&h1t[base + q1off];
      #pragma unroll
      for(int nt=0;nt<3;nt++){
        acc[yy][nt] = __builtin_amdgcn_mfma_f32_16x16x32_bf16(a0.s, Bf[nt][0].s, acc[yy][nt], 0,0,0);
        acc[yy][nt] = __builtin_amdgcn_mfma_f32_16x16x32_bf16(a1.s, Bf[nt][1].s, acc[yy][nt], 0,0,0);
      }
    }
  }
  float s[3]={0.f,0.f,0.f}, q[3]={0.f,0.f,0.f};
  size_t tilebase = ((size_t)(b*256 + blockIdx.x))*48*256;
  #pragma unroll
  for(int yy=0;yy<4;yy++){
    #pragma unroll
    for(int nt=0;nt<3;nt++){
      int oc = nt*16 + n;
      size_t base = tilebase + (size_t)oc*256 + (w*4+yy)*16 + quad*4;
      us4 u;
      #pragma unroll
      for(int r=0;r<4;r++){
        float v=tanhf_(acc[yy][nt][r]);
        u[r]=f2bf(v);
        float vb=bf2f(u[r]);
        s[nt]+=vb; q[nt]+=vb*vb;
      }
      *(us4*)&h2t[base] = u;
    }
  }
  #pragma unroll
  for(int nt=0;nt<3;nt++){
    s[nt]+=__shfl_xor(s[nt],16,64); s[nt]+=__shfl_xor(s[nt],32,64);
    q[nt]+=__shfl_xor(q[nt],16,64); q[nt]+=__shfl_xor(q[nt],32,64);
  }
  if(quad==0){
    #pragma unroll
    for(int nt=0;nt<3;nt++){ red[w][nt][n][0]=s[nt]; red[w][nt][n][1]=q[nt]; }
  }
  __syncthreads();
  if(threadIdx.x<48){
    int oc=threadIdx.x; int nt=oc>>4, nn=oc&15;
    float S=red[0][nt][nn][0]+red[1][nt][nn][0]+red[2][nt][nn][0]+red[3][nt][nn][0];
    float Q=red[0][nt][nn][1]+red[1][nt][nn][1]+red[2][nt][nn][1]+red[3][nt][nn][1];
    atomicAdd(&stats[2*oc],S); atomicAdd(&stats[2*oc+1],Q);
  }
}

// ---------------- per-channel sum/sumsq ----------------
__global__ __launch_bounds__(256) void k_cstat(const float* srcf, const ushort_t* srch, int isbf,
      int C, int HWn, int Bn, int S, float* stats){
  int c = blockIdx.x % C; int s = blockIdx.x / C;
  float sum=0.f, sq=0.f;
  for(int b=0;b<Bn;b++){
    size_t base=((size_t)b*C+c)*HWn;
    for(int i=s*256+threadIdx.x; i<HWn; i+=S*256){
      float v = isbf ? bf2f(srch[base+i]) : srcf[base+i];
      sum+=v; sq+=v*v;
    }
  }
  for(int o=32;o;o>>=1){ sum+=__shfl_down(sum,o,64); sq+=__shfl_down(sq,o,64); }
  __shared__ float ls[4], lq[4];
  int wid=threadIdx.x>>6;
  if((threadIdx.x&63)==0){ ls[wid]=sum; lq[wid]=sq; }
  __syncthreads();
  if(threadIdx.x==0){
    atomicAdd(&stats[2*c],   ls[0]+ls[1]+ls[2]+ls[3]);
    atomicAdd(&stats[2*c+1], lq[0]+lq[1]+lq[2]+lq[3]);
  }
}

__global__ __launch_bounds__(64) void k_csb(const float* stats, const void* g, const void* b,
      const float* dfl, float invN, float* scale, float* bias){
  int c=threadIdx.x; if(c>=NC) return;
  int isbf = dfl[0]>0.5f;
  float mean=stats[2*c]*invN; float var=stats[2*c+1]*invN - mean*mean;
  float s=ldg_(g,c,isbf)*rsqrtf(var+1e-5f);
  scale[c]=s; bias[c]=ldg_(b,c,isbf)-s*mean;
}

// ---------------- CHANGE from tiled h2: one block per tile ----------------
__global__ __launch_bounds__(256) void k_change(const ushort_t* h2t,
      const float* wc2, const float* sc, const float* bi, float* CH){
  int tile = blockIdx.x;                 // b*256 + ti*16 + tj
  int b = tile>>8; int rest = tile&255; int ti = rest>>4, tj = rest&15;
  int t = threadIdx.x;
  int pix = t&63, icq = t>>6;            // 4 ic-groups of 12
  int oi = pix>>3, oj = pix&7;
  const ushort_t* tp = &h2t[(size_t)tile*48*256];
  float acc = 0.f;
  #pragma unroll
  for(int icl=0; icl<12; icl++){
    int ic = icq*12 + icl;
    float s = sc[ic], tb = bi[ic];
    const ushort_t* cp = tp + ic*256 + (2*oi)*16 + 2*oj;
    acc += tanhf_(s*bf2f(cp[0 ])+tb)*wc2[ic*4+0];
    acc += tanhf_(s*bf2f(cp[1 ])+tb)*wc2[ic*4+1];
    acc += tanhf_(s*bf2f(cp[16])+tb)*wc2[ic*4+2];
    acc += tanhf_(s*bf2f(cp[17])+tb)*wc2[ic*4+3];
  }
  __shared__ float rr[256];
  rr[icq*64+pix] = acc;
  __syncthreads();
  if(t<64){
    float v = rr[t]+rr[64+t]+rr[128+t]+rr[192+t];
    int i = ti*8 + (t>>3), j = tj*8 + (t&7);
    CH[((size_t)b<<14) + i*128 + j] = sigm_(v);
  }
}

// ---------------- t1 (bf16) ----------------
__global__ __launch_bounds__(256) void k_cm1(const void* x, const float* dfl, const float* w, ushort_t* t1){
  int isbf = dfl[0]>0.5f;
  int p=blockIdx.x*256+threadIdx.x;
  int b=p>>14; int rem=p&16383; int i=rem>>7; int j=rem&127;
  float v[6][2][2];
  #pragma unroll
  for(int d=0;d<6;d++)
    #pragma unroll
    for(int ki=0;ki<2;ki++)
      #pragma unroll
      for(int kj=0;kj<2;kj++)
        v[d][ki][kj]=ldg_(x, ((size_t)(b*6+d)*HH + 2*i+ki)*WW + 2*j+kj, isbf);
  for(int oc=0;oc<NC;oc++){
    int g=oc>>4;
    float a=0.f;
    #pragma unroll
    for(int icl=0;icl<2;icl++)
      #pragma unroll
      for(int ki=0;ki<2;ki++)
        #pragma unroll
        for(int kj=0;kj<2;kj++)
          a += v[2*g+icl][ki][kj]*w[((oc*2+icl)*2+ki)*2+kj];
    t1[((size_t)(b*NC+oc)*HW2) + rem]=f2bf(a);
  }
}

// ---------------- t2: 16x16 tiles, group in z ----------------
__global__ __launch_bounds__(256) void k_cm2(const ushort_t* t1, const float* sc, const float* bi,
        const float* wct, float* t2){
  __shared__ float as[16][20][21];
  int b=blockIdx.y, g=blockIdx.z;
  int ti=blockIdx.x/9, tj=blockIdx.x%9;
  int i0=ti*16, j0=tj*16;
  int ty=threadIdx.x>>4, tx=threadIdx.x&15;
  for(int idx=threadIdx.x; idx<6400; idx+=256){
    int i=idx/400; int rem=idx-i*400; int r=rem/20; int cc=rem-r*20;
    int cg=g*16+i;
    int y=i0-2+r, xx=j0-2+cc;
    float v=0.f;
    if(y>=0 && y<H2 && xx>=0 && xx<H2)
      v = tanhf_(sc[cg]*bf2f(t1[((size_t)(b*NC+cg)*H2 + y)*H2 + xx]) + bi[cg]);
    as[i][r][cc]=v;
  }
  __syncthreads();
  float acc[16];
  #pragma unroll
  for(int o=0;o<16;o++) acc[o]=0.f;
  for(int i=0;i<16;i++){
    float p[3][3];
    #pragma unroll
    for(int ki=0;ki<3;ki++)
      #pragma unroll
      for(int kj=0;kj<3;kj++) p[ki][kj]=as[i][ty+ki][tx+kj];
    #pragma unroll
    for(int o=0;o<16;o++){
      const float* wp=&wct[((size_t)(g*16+o)*16+i)*9];
      float a=0.f;
      #pragma unroll
      for(int q=0;q<9;q++) a += p[q/3][q%3]*wp[q];
      acc[o]+=a;
    }
  }
  int ii=i0+ty, jj=j0+tx;
  if(ii<130 && jj<130){
    #pragma unroll
    for(int o=0;o<16;o++)
      t2[((size_t)(b*NC+g*16+o)*130 + ii)*130 + jj]=tanhf_(acc[o]);
  }
}

// ---------------- xm: group in z ----------------
__global__ __launch_bounds__(256) void k_cm3(const float* t2, const float* w, float* xm){
  __shared__ float ts[16][18][20];
  int b=blockIdx.y, g=blockIdx.z;
  int ti=blockIdx.x>>3, tj=blockIdx.x&7;
  int i0=ti*16, j0=tj*16;
  int ty=threadIdx.x>>4, tx=threadIdx.x&15;
  for(int idx=threadIdx.x; idx<16*18*18; idx+=256){
    int i=idx/324; int rem=idx-i*324; int r=rem/18; int cc=rem-r*18;
    int cg=g*16+i;
    ts[i][r][cc]=t2[((size_t)(b*NC+cg)*130 + i0+r)*130 + j0+cc];
  }
  __syncthreads();
  float acc[2]={0.f,0.f};
  for(int icl=0;icl<16;icl++){
    float p[3][3];
    #pragma unroll
    for(int ki=0;ki<3;ki++)
      #pragma unroll
      for(int kj=0;kj<3;kj++) p[ki][kj]=ts[icl][ty+ki][tx+kj];
    #pragma unroll
    for(int ol=0;ol<2;ol++){
      int oc=2*g+ol;
      const float* wp=&w[((size_t)oc*16+icl)*9];
      float a=0.f;
      #pragma unroll
      for(int q=0;q<9;q++) a += p[q/3][q%3]*wp[q];
      acc[ol]+=a;
    }
  }
  int ii=i0+ty, jj=j0+tx;
  #pragma unroll
  for(int ol=0;ol<2;ol++)
    xm[((size_t)(b*6+2*g+ol)*H2 + ii)*H2 + jj]=tanhf_(acc[ol]);
}

// ---------------- final ----------------
__global__ __launch_bounds__(256) void k_final(const float* xm, const float* CH, const float* w1,
      const float* w2, const float* sc, const float* bi, const float* dfl, void* outp){
  int isbf = dfl[0]>0.5f;
  int p=blockIdx.x*256+threadIdx.x;
  int b=p>>14; int rem=p&16383;
  float v[6];
  #pragma unroll
  for(int d=0;d<6;d++) v[d]=xm[((size_t)(b*6+d)*HW2)+rem];
  float born[6]={0.f,0.f,0.f,0.f,0.f,0.f};
  for(int c=0;c<NC;c++){
    float y=0.f;
    #pragma unroll
    for(int d=0;d<6;d++) y+=w1[c*6+d]*v[d];
    float a=tanhf_(sc[c]*y+bi[c]);
    #pragma unroll
    for(int d=0;d<6;d++) born[d]+=w2[d*NC+c]*a;
  }
  float C=CH[p];
  #pragma unroll
  for(int d=0;d<6;d++){
    float o=v[d]*(1.f-C)+C*born[d];
    if(d<3) o=sigm_(o);
    size_t id=((size_t)(b*6+d)*HW2)+rem;
    if(isbf) ((ushort_t*)outp)[id]=f2bf(o); else ((float*)outp)[id]=o;
  }
}

extern "C" void kernel_launch(void* const* d_in, const int* in_sizes, int n_in,
                              void* d_out, int out_size, void* d_ws, size_t ws_size,
                              hipStream_t stream){
  (void)in_sizes; (void)n_in; (void)out_size; (void)ws_size;
  const ushort_t* x    = (const ushort_t*)d_in[0];
  const ushort_t* cew1 = (const ushort_t*)d_in[1];
  const void*     ceg  = d_in[2];
  const void*     ceb  = d_in[3];
  const ushort_t* cew2 = (const ushort_t*)d_in[4];
  const ushort_t* mdct = (const ushort_t*)d_in[5];
  const ushort_t* mdc1 = (const ushort_t*)d_in[6];
  const void*     mdg  = d_in[7];
  const void*     mdb  = d_in[8];
  const ushort_t* mdc2 = (const ushort_t*)d_in[9];
  const ushort_t* cmw1 = (const ushort_t*)d_in[10];
  const void*     cmg  = d_in[11];
  const void*     cmb  = d_in[12];
  const ushort_t* cmct = (const ushort_t*)d_in[13];
  const ushort_t* cmc2 = (const ushort_t*)d_in[14];
  const ushort_t* bow1 = (const ushort_t*)d_in[15];
  const void*     bog  = d_in[16];
  const void*     bob  = d_in[17];
  const ushort_t* bow2 = (const ushort_t*)d_in[18];
  float* ws = (float*)d_ws;

  const long OW_mdct=0, OW_mdc1=4320, OW_cew1=25056, OW_cew2=25344, OW_mdc2=25392,
             OW_cmw1=25584, OW_cmct=25968, OW_cmc2=32880, OW_bow1=33744, OW_bow2=34032;
  const long OFF_STATS=34320;
  const long ST_xmom=OFF_STATS+0,  ST_cesc=OFF_STATS+64,  ST_cebi=OFF_STATS+112,
             ST_h2  =OFF_STATS+160, ST_mdsc=OFF_STATS+256, ST_mdbi=OFF_STATS+304,
             ST_t1  =OFF_STATS+352, ST_cmsc=OFF_STATS+448, ST_cmbi=OFF_STATS+496,
             ST_xmm =OFF_STATS+544, ST_bosc=OFF_STATS+608, ST_bobi=OFF_STATS+656,
             ST_FLAG=OFF_STATS+960;
  const long OFF_WB2 = OFF_STATS + 1024;
  const long OFF_WB1 = OFF_WB2 + 13824;
  const long OFF_E   = OFF_WB1 + 6912;
  const long OFF_H2  = OFF_E + 524288L;        // h2 tiled bf16: 12582912 float-slots
  const long OFF_D   = OFF_H2 + 12582912L;     // t1/t2/xm/CH
  const long OFF_T1=OFF_D, OFF_T2=OFF_D+6291456L, OFF_XM=OFF_D+12781056L, OFF_CH=OFF_D+13567488L;

  ushort_t* h2t  = (ushort_t*)(ws + OFF_H2);
  ushort_t* t1h  = (ushort_t*)(ws + OFF_T1);
  ushort_t* wb2  = (ushort_t*)(ws + OFF_WB2);
  ushort_t* wb1  = (ushort_t*)(ws + OFF_WB1);
  const float* dfl = ws + ST_FLAG;

  (void)hipMemsetAsync(ws + OFF_STATS, 0, 1024*sizeof(float), stream);
  hipLaunchKernelGGL(k_detect, dim3(1), 256, 0, stream, x, ws+ST_FLAG);

  WC wc;
  const ushort_t* srcs[10] = {mdct,mdc1,cew1,cew2,mdc2,cmw1,cmct,cmc2,bow1,bow2};
  const int offs[10] = {(int)OW_mdct,(int)OW_mdc1,(int)OW_cew1,(int)OW_cew2,(int)OW_mdc2,
                        (int)OW_cmw1,(int)OW_cmct,(int)OW_cmc2,(int)OW_bow1,(int)OW_bow2};
  const int cnts[10] = {4320,20736,288,48,192,384,6912,864,288,288};
  for(int i=0;i<10;i++){ wc.src[i]=srcs[i]; wc.off[i]=offs[i]; wc.n[i]=cnts[i]; }
  hipLaunchKernelGGL(k_wcvt, dim3(81,10), 256, 0, stream, wc, ws, dfl);
  hipLaunchKernelGGL(k_wprep, dim3(21), 256, 0, stream, ws+OW_mdc1, ws+OW_mdct, wb2, wb1);

  // compenv
  hipLaunchKernelGGL(k_mom, dim3(256), 256, 0, stream, (const void*)x, dfl, 0, 16, B8*HWp, ws+ST_xmom);
  hipLaunchKernelGGL(k_msb, dim3(1), 64, 0, stream, ws+ST_xmom, ws+OW_cew1, ceg, ceb, dfl,
                     1.f/(float)(B8*HWp), ws+ST_cesc, ws+ST_cebi);
  hipLaunchKernelGGL(k_env, dim3(2048), 256, 0, stream, (const void*)x, dfl, ws+OW_cew1, ws+OW_cew2,
                     ws+ST_cesc, ws+ST_cebi, ws+OFF_E);

  // md chain: fused h1+h2 (h1 LDS-resident), tiled h2, fused stats
  hipLaunchKernelGGL(k_md, dim3(256,8), 256, 0, stream, (const void*)x, dfl, ws+OFF_E,
                     wb1, wb2, h2t, ws+ST_h2);
  hipLaunchKernelGGL(k_csb, dim3(1), 64, 0, stream, ws+ST_h2, mdg, mdb, dfl, 1.f/(float)(B8*HWp),
                     ws+ST_mdsc, ws+ST_mdbi);
  hipLaunchKernelGGL(k_change, dim3(2048), 256, 0, stream, h2t, ws+OW_mdc2,
                     ws+ST_mdsc, ws+ST_mdbi, ws+OFF_CH);

  // cm chain
  hipLaunchKernelGGL(k_cm1, dim3(512), 256, 0, stream, (const void*)x, dfl, ws+OW_cmw1, t1h);
  hipLaunchKernelGGL(k_cstat, dim3(48*8), 256, 0, stream, (const float*)nullptr, t1h, 1,
                     NC, HW2, B8, 8, ws+ST_t1);
  hipLaunchKernelGGL(k_csb, dim3(1), 64, 0, stream, ws+ST_t1, cmg, cmb, dfl, 1.f/(float)(B8*HW2),
                     ws+ST_cmsc, ws+ST_cmbi);
  hipLaunchKernelGGL(k_cm2, dim3(81,8,3), 256, 0, stream, t1h, ws+ST_cmsc, ws+ST_cmbi,
                     ws+OW_cmct, ws+OFF_T2);
  hipLaunchKernelGGL(k_cm3, dim3(64,8,3), 256, 0, stream, ws+OFF_T2, ws+OW_cmc2, ws+OFF_XM);

  // born + blend
  hipLaunchKernelGGL(k_mom, dim3(128), 256, 0, stream, (const void*)(ws+OFF_XM), (const float*)nullptr, 0,
                     14, B8*HW2, ws+ST_xmm);
  hipLaunchKernelGGL(k_msb, dim3(1), 64, 0, stream, ws+ST_xmm, ws+OW_bow1, bog, bob, dfl,
                     1.f/(float)(B8*HW2), ws+ST_bosc, ws+ST_bobi);
  hipLaunchKernelGGL(k_final, dim3(512), 256, 0, stream, ws+OFF_XM, ws+OFF_CH, ws+OW_bow1,
                     ws+OW_bow2, ws+ST_bosc, ws+ST_bobi, dfl, d_out);
}

// Round 12
// 444.910 us; speedup vs baseline: 1.1011x; 1.0074x over previous
//
#include <hip/hip_runtime.h>
#include <stdint.h>

typedef unsigned short ushort_t;

#define B8  8
#define D6  6
#define NC  48
#define HH  256
#define WW  256
#define HWp 65536
#define H2  128
#define HW2 16384

__device__ __constant__ int c_T0[8] = {0,1,1,1,0,-1,-1,-1};
__device__ __constant__ int c_T1[8] = {1,1,0,-1,-1,-1,0,1};

__device__ inline float bf2f(ushort_t u){ union{unsigned int i; float f;} w; w.i = ((unsigned int)u)<<16; return w.f; }
__device__ inline ushort_t f2bf(float f){ union{float f; unsigned int i;} w; w.f=f; unsigned int xx=w.i;
  return (ushort_t)((xx + 0x7fffu + ((xx>>16)&1u)) >> 16); }
__device__ inline float tanhf_(float x){ float e=__expf(2.f*x); return 1.f - 2.f/(e+1.f); }
__device__ inline float sigm_(float x){ return 1.f/(1.f+__expf(-x)); }
__device__ inline float ldg_(const void* p, size_t i, int isbf){
  return isbf ? bf2f(((const ushort_t*)p)[i]) : ((const float*)p)[i];
}

typedef short short8 __attribute__((ext_vector_type(8)));
typedef float f4 __attribute__((ext_vector_type(4)));
typedef ushort_t us4 __attribute__((ext_vector_type(4)));
typedef ushort_t us8 __attribute__((ext_vector_type(8)));
union AB { short8 s; us4 h[2]; us8 u; };

#define TE_S  18   // te stride (ushorts), 9 dwords odd -> conflict-free
#define H1_S  50   // h1t stride (ushorts), 25 dwords odd -> conflict-free

// ---------------- dtype detection ----------------
__global__ __launch_bounds__(256) void k_detect(const ushort_t* x, float* flag){
  int t=threadIdx.x; int cnt=0;
  for(int i=t;i<4096;i+=256){
    ushort_t u=x[2*i];
    int e=(u>>7)&0xff;
    if(e>=100 && e<=150) cnt++;
  }
  for(int o=32;o;o>>=1) cnt+=__shfl_down(cnt,o,64);
  __shared__ int sh4[4];
  if((t&63)==0) sh4[t>>6]=cnt;
  __syncthreads();
  if(t==0){ int tot=sh4[0]+sh4[1]+sh4[2]+sh4[3]; flag[0] = (tot>=2048)?1.f:0.f; }
}

// ---------------- weight conversion to fp32 ----------------
struct WC { const ushort_t* src[10]; int off[10]; int n[10]; };

__global__ __launch_bounds__(256) void k_wcvt(WC wc, float* dst, const float* dfl){
  int isbf = dfl[0]>0.5f;
  int t = blockIdx.y; int n = wc.n[t]; const ushort_t* s = wc.src[t]; float* d = dst + wc.off[t];
  for(int i = blockIdx.x*256 + threadIdx.x; i < n; i += gridDim.x*256)
    d[i] = isbf ? bf2f(s[i]) : ((const float*)s)[i];
}

// ---------------- MFMA weight prep ----------------
__global__ __launch_bounds__(256) void k_wprep(const float* w2src, const float* w1src,
                                               ushort_t* wb2, ushort_t* wb1){
  int t = blockIdx.x*256+threadIdx.x;
  if(t<3456){
    int lane=t&63; int rest=t>>6;
    int ks=rest&1; int g=rest>>1; int tap=g%9; int nt=g/9;
    int oc=nt*16+(lane&15); int icb=ks*32+((lane>>4)*8);
    #pragma unroll
    for(int j=0;j<8;j++){
      int ic=icb+j;
      float v = (ic<48) ? w2src[(oc*48+ic)*9+tap] : 0.f;
      wb2[(size_t)t*8+j]=f2bf(v);
    }
  } else if(t<5184){
    int tt=t-3456; int lane=tt&63; int g=tt>>6; int tap=g%9; int nt=g/9;
    int oc=nt*16+(lane&15); int icb=(lane>>4)*8;
    #pragma unroll
    for(int j=0;j<8;j++){
      int ic=icb+j;
      float v = (ic<10) ? w1src[(oc*10+ic)*9+tap] : 0.f;
      wb1[(size_t)tt*8+j]=f2bf(v);
    }
  }
}

// ---------------- 6-channel moment reduction ----------------
__global__ __launch_bounds__(256) void k_mom(const void* src, const float* dfl, int isbfc,
                                             int sh, int npix, float* out){
  int isbf = dfl ? (dfl[0]>0.5f) : isbfc;
  float vals[27];
  #pragma unroll
  for(int i=0;i<27;i++) vals[i]=0.f;
  int stride = gridDim.x*256;
  int msk = (1<<sh)-1;
  for(int p = blockIdx.x*256+threadIdx.x; p < npix; p += stride){
    int b = p >> sh; int hw = p & msk;
    float v[6];
    #pragma unroll
    for(int d=0; d<6; d++){
      size_t idx = (((size_t)(b*6+d))<<sh) + hw;
      v[d] = ldg_(src, idx, isbf);
    }
    int q=6;
    #pragma unroll
    for(int d=0;d<6;d++){
      vals[d]+=v[d];
      #pragma unroll
      for(int e=d;e<6;e++){ vals[q] += v[d]*v[e]; q++; }
    }
  }
  __shared__ float red[4][27];
  int wid=threadIdx.x>>6, lane=threadIdx.x&63;
  #pragma unroll
  for(int i=0;i<27;i++){
    float v=vals[i];
    for(int o=32;o;o>>=1) v+=__shfl_down(v,o,64);
    if(lane==0) red[wid][i]=v;
  }
  __syncthreads();
  if(threadIdx.x<27)
    atomicAdd(&out[threadIdx.x],
      red[0][threadIdx.x]+red[1][threadIdx.x]+red[2][threadIdx.x]+red[3][threadIdx.x]);
}

__global__ __launch_bounds__(64) void k_msb(const float* mom, const float* W1,
      const void* g, const void* b, const float* dfl, float invN, float* scale, float* bias){
  int c = threadIdx.x; if(c>=NC) return;
  int isbf = dfl[0]>0.5f;
  const int st[6]={0,6,11,15,18,20};
  float wr[6];
  #pragma unroll
  for(int d=0;d<6;d++) wr[d]=W1[c*6+d];
  float mean=0.f;
  #pragma unroll
  for(int d=0;d<6;d++) mean += wr[d]*mom[d];
  mean *= invN;
  float e2=0.f;
  #pragma unroll
  for(int d=0;d<6;d++){
    #pragma unroll
    for(int e=d;e<6;e++){
      float mm = mom[6 + st[d] + (e-d)];
      e2 += wr[d]*wr[e]*((e==d)?1.f:2.f)*mm;
    }
  }
  e2 *= invN;
  float var = e2 - mean*mean;
  float sc = ldg_(g,c,isbf) * rsqrtf(var + 1e-5f);
  scale[c]=sc; bias[c]= ldg_(b,c,isbf) - sc*mean;
}

// ---------------- compenv ----------------
__global__ __launch_bounds__(256) void k_env(const void* x, const float* dfl,
      const float* w1, const float* w2, const float* sc, const float* bi, float* e){
  int isbf = dfl[0]>0.5f;
  int p = blockIdx.x*256+threadIdx.x;
  int b = p >> 16; int hw = p & 65535;
  float v[6];
  #pragma unroll
  for(int d=0; d<6; d++) v[d]=ldg_(x,(size_t)(b*6+d)*HWp + hw, isbf);
  float acc=0.f;
  for(int c=0;c<NC;c++){
    float y=0.f;
    #pragma unroll
    for(int d=0;d<6;d++) y += w1[c*6+d]*v[d];
    acc += w2[c]*tanhf_(sc[c]*y + bi[c]);
  }
  e[(size_t)b*HWp + hw]=acc;
}

// ---------------- fused md: h1 (LDS) -> h2 -> TILED bf16 [tile][48][16][16] + BN stats ----------------
// Dead-K lanes (B==0) read offset 0 of the same pixel (finite tanh data) -> no zero tails.
__global__ __launch_bounds__(256,3) void k_md(const void* x, const float* dfl, const float* e,
      const ushort_t* wb1, const ushort_t* wb2, ushort_t* h2t, float* stats){
  __shared__ __attribute__((aligned(16))) ushort_t te[400*TE_S];    // [pix 20x20][18], ch>=10 zero
  __shared__ __attribute__((aligned(16))) ushort_t h1t[336*H1_S];   // [pix 336][50]
  __shared__ float red[4][3][16][2];
  int isbf = dfl[0]>0.5f;
  int b = blockIdx.y;
  int ti = blockIdx.x>>4, tj = blockIdx.x&15;
  int i0 = ti*16, j0 = tj*16;
  int lane = threadIdx.x&63, w = threadIdx.x>>6;
  int n = lane&15, quad = lane>>4;
  // phase 0: zero te (ch 10..17 must be finite-zero for quad1 reads)
  {
    us8 z;
    #pragma unroll
    for(int j=0;j<8;j++) z[j]=0;
    us8* tp=(us8*)te;
    for(int idx=threadIdx.x; idx<900; idx+=256) tp[idx]=z;
  }
  __syncthreads();
  // phase 1: stage te ch0..9 (x 2ch + rolled e 8ch)
  for(int idx=threadIdx.x; idx<4000; idx+=256){
    int pix = idx/10, ic = idx-pix*10;
    int r = pix/20, c = pix-r*20;
    int gy = i0-2+r, gx = j0-2+c;
    float v = 0.f;
    if(gy>=0 && gy<HH && gx>=0 && gx<WW){
      if(ic<2) v = ldg_(x, ((size_t)(b*6+ic)*HH + gy)*WW + gx, isbf);
      else { int k=ic-2;
        int yy=(gy + c_T1[k]) & 255; int xx=(gx - c_T0[k]) & 255;
        v = e[((size_t)b*HH + yy)*WW + xx]; }
    }
    te[pix*TE_S+ic]=f2bf(v);
  }
  __syncthreads();
  // phase 2: h1 = tanh(conv3x3(te,pad2)) -> h1t[18x18][50], 21 m-tiles over waves
  {
    int qoff = (quad==1) ? 8 : 0;   // quads 2,3: B=0, reuse offset 0 (finite)
    for(int mt=w; mt<21; mt+=4){
      int p = mt*16 + n;            // linear pixel (garbage beyond 323 -> unused slots)
      int pr = p/18, pc = p-pr*18;
      f4 hacc[3];
      #pragma unroll
      for(int nt=0;nt<3;nt++) hacc[nt]=(f4){0.f,0.f,0.f,0.f};
      #pragma unroll
      for(int tap=0; tap<9; tap++){
        int ki=tap/3, kj=tap%3;
        AB a; a.u = *(const us8*)&te[((pr+ki)*20 + pc+kj)*TE_S + qoff];
        #pragma unroll
        for(int nt=0;nt<3;nt++){
          AB Bf; Bf.u = *(const us8*)&wb1[((size_t)((nt*9+tap)*64+lane))*8];
          hacc[nt] = __builtin_amdgcn_mfma_f32_16x16x32_bf16(a.s, Bf.s, hacc[nt], 0,0,0);
        }
      }
      int pd = mt*16 + quad*4;      // D rows: pixel = mt*16 + quad*4 + reg
      #pragma unroll
      for(int nt=0;nt<3;nt++){
        #pragma unroll
        for(int r=0;r<4;r++)
          h1t[(pd+r)*H1_S + nt*16 + n] = f2bf(tanhf_(hacc[nt][r]));
      }
    }
  }
  __syncthreads();
  // phase 3: h2 = tanh(conv3x3(h1t)) + stats
  f4 acc[4][3];
  #pragma unroll
  for(int a=0;a<4;a++)
    #pragma unroll
    for(int c=0;c<3;c++) acc[a][c]=(f4){0.f,0.f,0.f,0.f};
  int q1off = (quad<2) ? (32+quad*8) : 0;   // dead-K quads reuse offset 0 (finite, B=0)
  #pragma unroll
  for(int tap=0; tap<9; tap++){
    int ki=tap/3, kj=tap%3;
    AB Bf[3][2];
    #pragma unroll
    for(int nt=0;nt<3;nt++)
      #pragma unroll
      for(int ks=0;ks<2;ks++)
        Bf[nt][ks].u = *(const us8*)&wb2[((size_t)(((nt*9+tap)*2+ks)*64+lane))*8];
    #pragma unroll
    for(int yy=0; yy<4; yy++){
      int y = w*4 + yy;
      int base = ((y+ki)*18 + n + kj)*H1_S;
      AB a0, a1;
      a0.u = *(const us8*)&h1t[base + quad*8];
      a1.u = *(const us8*)&h1t[base + q1off];
      #pragma unroll
      for(int nt=0;nt<3;nt++){
        acc[yy][nt] = __builtin_amdgcn_mfma_f32_16x16x32_bf16(a0.s, Bf[nt][0].s, acc[yy][nt], 0,0,0);
        acc[yy][nt] = __builtin_amdgcn_mfma_f32_16x16x32_bf16(a1.s, Bf[nt][1].s, acc[yy][nt], 0,0,0);
      }
    }
  }
  float s[3]={0.f,0.f,0.f}, q[3]={0.f,0.f,0.f};
  size_t tilebase = ((size_t)(b*256 + blockIdx.x))*48*256;
  #pragma unroll
  for(int yy=0;yy<4;yy++){
    #pragma unroll
    for(int nt=0;nt<3;nt++){
      int oc = nt*16 + n;
      size_t base = tilebase + (size_t)oc*256 + (w*4+yy)*16 + quad*4;
      us4 u;
      #pragma unroll
      for(int r=0;r<4;r++){
        float v=tanhf_(acc[yy][nt][r]);
        u[r]=f2bf(v);
        float vb=bf2f(u[r]);
        s[nt]+=vb; q[nt]+=vb*vb;
      }
      *(us4*)&h2t[base] = u;
    }
  }
  #pragma unroll
  for(int nt=0;nt<3;nt++){
    s[nt]+=__shfl_xor(s[nt],16,64); s[nt]+=__shfl_xor(s[nt],32,64);
    q[nt]+=__shfl_xor(q[nt],16,64); q[nt]+=__shfl_xor(q[nt],32,64);
  }
  if(quad==0){
    #pragma unroll
    for(int nt=0;nt<3;nt++){ red[w][nt][n][0]=s[nt]; red[w][nt][n][1]=q[nt]; }
  }
  __syncthreads();
  if(threadIdx.x<48){
    int oc=threadIdx.x; int nt=oc>>4, nn=oc&15;
    float S=red[0][nt][nn][0]+red[1][nt][nn][0]+red[2][nt][nn][0]+red[3][nt][nn][0];
    float Q=red[0][nt][nn][1]+red[1][nt][nn][1]+red[2][nt][nn][1]+red[3][nt][nn][1];
    atomicAdd(&stats[2*oc],S); atomicAdd(&stats[2*oc+1],Q);
  }
}

// ---------------- per-channel sum/sumsq ----------------
__global__ __launch_bounds__(256) void k_cstat(const float* srcf, const ushort_t* srch, int isbf,
      int C, int HWn, int Bn, int S, float* stats){
  int c = blockIdx.x % C; int s = blockIdx.x / C;
  float sum=0.f, sq=0.f;
  for(int b=0;b<Bn;b++){
    size_t base=((size_t)b*C+c)*HWn;
    for(int i=s*256+threadIdx.x; i<HWn; i+=S*256){
      float v = isbf ? bf2f(srch[base+i]) : srcf[base+i];
      sum+=v; sq+=v*v;
    }
  }
  for(int o=32;o;o>>=1){ sum+=__shfl_down(sum,o,64); sq+=__shfl_down(sq,o,64); }
  __shared__ float ls[4], lq[4];
  int wid=threadIdx.x>>6;
  if((threadIdx.x&63)==0){ ls[wid]=sum; lq[wid]=sq; }
  __syncthreads();
  if(threadIdx.x==0){
    atomicAdd(&stats[2*c],   ls[0]+ls[1]+ls[2]+ls[3]);
    atomicAdd(&stats[2*c+1], lq[0]+lq[1]+lq[2]+lq[3]);
  }
}

__global__ __launch_bounds__(64) void k_csb(const float* stats, const void* g, const void* b,
      const float* dfl, float invN, float* scale, float* bias){
  int c=threadIdx.x; if(c>=NC) return;
  int isbf = dfl[0]>0.5f;
  float mean=stats[2*c]*invN; float var=stats[2*c+1]*invN - mean*mean;
  float s=ldg_(g,c,isbf)*rsqrtf(var+1e-5f);
  scale[c]=s; bias[c]=ldg_(b,c,isbf)-s*mean;
}

// ---------------- CHANGE from tiled h2: one block per tile ----------------
__global__ __launch_bounds__(256) void k_change(const ushort_t* h2t,
      const float* wc2, const float* sc, const float* bi, float* CH){
  int tile = blockIdx.x;                 // b*256 + ti*16 + tj
  int b = tile>>8; int rest = tile&255; int ti = rest>>4, tj = rest&15;
  int t = threadIdx.x;
  int pix = t&63, icq = t>>6;            // 4 ic-groups of 12
  int oi = pix>>3, oj = pix&7;
  const ushort_t* tp = &h2t[(size_t)tile*48*256];
  float acc = 0.f;
  #pragma unroll
  for(int icl=0; icl<12; icl++){
    int ic = icq*12 + icl;
    float s = sc[ic], tb = bi[ic];
    const ushort_t* cp = tp + ic*256 + (2*oi)*16 + 2*oj;
    acc += tanhf_(s*bf2f(cp[0 ])+tb)*wc2[ic*4+0];
    acc += tanhf_(s*bf2f(cp[1 ])+tb)*wc2[ic*4+1];
    acc += tanhf_(s*bf2f(cp[16])+tb)*wc2[ic*4+2];
    acc += tanhf_(s*bf2f(cp[17])+tb)*wc2[ic*4+3];
  }
  __shared__ float rr[256];
  rr[icq*64+pix] = acc;
  __syncthreads();
  if(t<64){
    float v = rr[t]+rr[64+t]+rr[128+t]+rr[192+t];
    int i = ti*8 + (t>>3), j = tj*8 + (t&7);
    CH[((size_t)b<<14) + i*128 + j] = sigm_(v);
  }
}

// ---------------- t1 (bf16) ----------------
__global__ __launch_bounds__(256) void k_cm1(const void* x, const float* dfl, const float* w, ushort_t* t1){
  int isbf = dfl[0]>0.5f;
  int p=blockIdx.x*256+threadIdx.x;
  int b=p>>14; int rem=p&16383; int i=rem>>7; int j=rem&127;
  float v[6][2][2];
  #pragma unroll
  for(int d=0;d<6;d++)
    #pragma unroll
    for(int ki=0;ki<2;ki++)
      #pragma unroll
      for(int kj=0;kj<2;kj++)
        v[d][ki][kj]=ldg_(x, ((size_t)(b*6+d)*HH + 2*i+ki)*WW + 2*j+kj, isbf);
  for(int oc=0;oc<NC;oc++){
    int g=oc>>4;
    float a=0.f;
    #pragma unroll
    for(int icl=0;icl<2;icl++)
      #pragma unroll
      for(int ki=0;ki<2;ki++)
        #pragma unroll
        for(int kj=0;kj<2;kj++)
          a += v[2*g+icl][ki][kj]*w[((oc*2+icl)*2+ki)*2+kj];
    t1[((size_t)(b*NC+oc)*HW2) + rem]=f2bf(a);
  }
}

// ---------------- t2: 16x16 tiles, group in z ----------------
__global__ __launch_bounds__(256) void k_cm2(const ushort_t* t1, const float* sc, const float* bi,
        const float* wct, float* t2){
  __shared__ float as[16][20][21];
  int b=blockIdx.y, g=blockIdx.z;
  int ti=blockIdx.x/9, tj=blockIdx.x%9;
  int i0=ti*16, j0=tj*16;
  int ty=threadIdx.x>>4, tx=threadIdx.x&15;
  for(int idx=threadIdx.x; idx<6400; idx+=256){
    int i=idx/400; int rem=idx-i*400; int r=rem/20; int cc=rem-r*20;
    int cg=g*16+i;
    int y=i0-2+r, xx=j0-2+cc;
    float v=0.f;
    if(y>=0 && y<H2 && xx>=0 && xx<H2)
      v = tanhf_(sc[cg]*bf2f(t1[((size_t)(b*NC+cg)*H2 + y)*H2 + xx]) + bi[cg]);
    as[i][r][cc]=v;
  }
  __syncthreads();
  float acc[16];
  #pragma unroll
  for(int o=0;o<16;o++) acc[o]=0.f;
  for(int i=0;i<16;i++){
    float p[3][3];
    #pragma unroll
    for(int ki=0;ki<3;ki++)
      #pragma unroll
      for(int kj=0;kj<3;kj++) p[ki][kj]=as[i][ty+ki][tx+kj];
    #pragma unroll
    for(int o=0;o<16;o++){
      const float* wp=&wct[((size_t)(g*16+o)*16+i)*9];
      float a=0.f;
      #pragma unroll
      for(int q=0;q<9;q++) a += p[q/3][q%3]*wp[q];
      acc[o]+=a;
    }
  }
  int ii=i0+ty, jj=j0+tx;
  if(ii<130 && jj<130){
    #pragma unroll
    for(int o=0;o<16;o++)
      t2[((size_t)(b*NC+g*16+o)*130 + ii)*130 + jj]=tanhf_(acc[o]);
  }
}

// ---------------- xm: group in z ----------------
__global__ __launch_bounds__(256) void k_cm3(const float* t2, const float* w, float* xm){
  __shared__ float ts[16][18][20];
  int b=blockIdx.y, g=blockIdx.z;
  int ti=blockIdx.x>>3, tj=blockIdx.x&7;
  int i0=ti*16, j0=tj*16;
  int ty=threadIdx.x>>4, tx=threadIdx.x&15;
  for(int idx=threadIdx.x; idx<16*18*18; idx+=256){
    int i=idx/324; int rem=idx-i*324; int r=rem/18; int cc=rem-r*18;
    int cg=g*16+i;
    ts[i][r][cc]=t2[((size_t)(b*NC+cg)*130 + i0+r)*130 + j0+cc];
  }
  __syncthreads();
  float acc[2]={0.f,0.f};
  for(int icl=0;icl<16;icl++){
    float p[3][3];
    #pragma unroll
    for(int ki=0;ki<3;ki++)
      #pragma unroll
      for(int kj=0;kj<3;kj++) p[ki][kj]=ts[icl][ty+ki][tx+kj];
    #pragma unroll
    for(int ol=0;ol<2;ol++){
      int oc=2*g+ol;
      const float* wp=&w[((size_t)oc*16+icl)*9];
      float a=0.f;
      #pragma unroll
      for(int q=0;q<9;q++) a += p[q/3][q%3]*wp[q];
      acc[ol]+=a;
    }
  }
  int ii=i0+ty, jj=j0+tx;
  #pragma unroll
  for(int ol=0;ol<2;ol++)
    xm[((size_t)(b*6+2*g+ol)*H2 + ii)*H2 + jj]=tanhf_(acc[ol]);
}

// ---------------- final ----------------
__global__ __launch_bounds__(256) void k_final(const float* xm, const float* CH, const float* w1,
      const float* w2, const float* sc, const float* bi, const float* dfl, void* outp){
  int isbf = dfl[0]>0.5f;
  int p=blockIdx.x*256+threadIdx.x;
  int b=p>>14; int rem=p&16383;
  float v[6];
  #pragma unroll
  for(int d=0;d<6;d++) v[d]=xm[((size_t)(b*6+d)*HW2)+rem];
  float born[6]={0.f,0.f,0.f,0.f,0.f,0.f};
  for(int c=0;c<NC;c++){
    float y=0.f;
    #pragma unroll
    for(int d=0;d<6;d++) y+=w1[c*6+d]*v[d];
    float a=tanhf_(sc[c]*y+bi[c]);
    #pragma unroll
    for(int d=0;d<6;d++) born[d]+=w2[d*NC+c]*a;
  }
  float C=CH[p];
  #pragma unroll
  for(int d=0;d<6;d++){
    float o=v[d]*(1.f-C)+C*born[d];
    if(d<3) o=sigm_(o);
    size_t id=((size_t)(b*6+d)*HW2)+rem;
    if(isbf) ((ushort_t*)outp)[id]=f2bf(o); else ((float*)outp)[id]=o;
  }
}

extern "C" void kernel_launch(void* const* d_in, const int* in_sizes, int n_in,
                              void* d_out, int out_size, void* d_ws, size_t ws_size,
                              hipStream_t stream){
  (void)in_sizes; (void)n_in; (void)out_size; (void)ws_size;
  const ushort_t* x    = (const ushort_t*)d_in[0];
  const ushort_t* cew1 = (const ushort_t*)d_in[1];
  const void*     ceg  = d_in[2];
  const void*     ceb  = d_in[3];
  const ushort_t* cew2 = (const ushort_t*)d_in[4];
  const ushort_t* mdct = (const ushort_t*)d_in[5];
  const ushort_t* mdc1 = (const ushort_t*)d_in[6];
  const void*     mdg  = d_in[7];
  const void*     mdb  = d_in[8];
  const ushort_t* mdc2 = (const ushort_t*)d_in[9];
  const ushort_t* cmw1 = (const ushort_t*)d_in[10];
  const void*     cmg  = d_in[11];
  const void*     cmb  = d_in[12];
  const ushort_t* cmct = (const ushort_t*)d_in[13];
  const ushort_t* cmc2 = (const ushort_t*)d_in[14];
  const ushort_t* bow1 = (const ushort_t*)d_in[15];
  const void*     bog  = d_in[16];
  const void*     bob  = d_in[17];
  const ushort_t* bow2 = (const ushort_t*)d_in[18];
  float* ws = (float*)d_ws;

  const long OW_mdct=0, OW_mdc1=4320, OW_cew1=25056, OW_cew2=25344, OW_mdc2=25392,
             OW_cmw1=25584, OW_cmct=25968, OW_cmc2=32880, OW_bow1=33744, OW_bow2=34032;
  const long OFF_STATS=34320;
  const long ST_xmom=OFF_STATS+0,  ST_cesc=OFF_STATS+64,  ST_cebi=OFF_STATS+112,
             ST_h2  =OFF_STATS+160, ST_mdsc=OFF_STATS+256, ST_mdbi=OFF_STATS+304,
             ST_t1  =OFF_STATS+352, ST_cmsc=OFF_STATS+448, ST_cmbi=OFF_STATS+496,
             ST_xmm =OFF_STATS+544, ST_bosc=OFF_STATS+608, ST_bobi=OFF_STATS+656,
             ST_FLAG=OFF_STATS+960;
  const long OFF_WB2 = OFF_STATS + 1024;
  const long OFF_WB1 = OFF_WB2 + 13824;
  const long OFF_E   = OFF_WB1 + 6912;
  const long OFF_H2  = OFF_E + 524288L;        // h2 tiled bf16: 12582912 float-slots
  const long OFF_D   = OFF_H2 + 12582912L;     // t1/t2/xm/CH
  const long OFF_T1=OFF_D, OFF_T2=OFF_D+6291456L, OFF_XM=OFF_D+12781056L, OFF_CH=OFF_D+13567488L;

  ushort_t* h2t  = (ushort_t*)(ws + OFF_H2);
  ushort_t* t1h  = (ushort_t*)(ws + OFF_T1);
  ushort_t* wb2  = (ushort_t*)(ws + OFF_WB2);
  ushort_t* wb1  = (ushort_t*)(ws + OFF_WB1);
  const float* dfl = ws + ST_FLAG;

  (void)hipMemsetAsync(ws + OFF_STATS, 0, 1024*sizeof(float), stream);
  hipLaunchKernelGGL(k_detect, dim3(1), 256, 0, stream, x, ws+ST_FLAG);

  WC wc;
  const ushort_t* srcs[10] = {mdct,mdc1,cew1,cew2,mdc2,cmw1,cmct,cmc2,bow1,bow2};
  const int offs[10] = {(int)OW_mdct,(int)OW_mdc1,(int)OW_cew1,(int)OW_cew2,(int)OW_mdc2,
                        (int)OW_cmw1,(int)OW_cmct,(int)OW_cmc2,(int)OW_bow1,(int)OW_bow2};
  const int cnts[10] = {4320,20736,288,48,192,384,6912,864,288,288};
  for(int i=0;i<10;i++){ wc.src[i]=srcs[i]; wc.off[i]=offs[i]; wc.n[i]=cnts[i]; }
  hipLaunchKernelGGL(k_wcvt, dim3(81,10), 256, 0, stream, wc, ws, dfl);
  hipLaunchKernelGGL(k_wprep, dim3(21), 256, 0, stream, ws+OW_mdc1, ws+OW_mdct, wb2, wb1);

  // compenv
  hipLaunchKernelGGL(k_mom, dim3(256), 256, 0, stream, (const void*)x, dfl, 0, 16, B8*HWp, ws+ST_xmom);
  hipLaunchKernelGGL(k_msb, dim3(1), 64, 0, stream, ws+ST_xmom, ws+OW_cew1, ceg, ceb, dfl,
                     1.f/(float)(B8*HWp), ws+ST_cesc, ws+ST_cebi);
  hipLaunchKernelGGL(k_env, dim3(2048), 256, 0, stream, (const void*)x, dfl, ws+OW_cew1, ws+OW_cew2,
                     ws+ST_cesc, ws+ST_cebi, ws+OFF_E);

  // md chain: fused h1+h2 (h1 LDS-resident), tiled h2, fused stats
  hipLaunchKernelGGL(k_md, dim3(256,8), 256, 0, stream, (const void*)x, dfl, ws+OFF_E,
                     wb1, wb2, h2t, ws+ST_h2);
  hipLaunchKernelGGL(k_csb, dim3(1), 64, 0, stream, ws+ST_h2, mdg, mdb, dfl, 1.f/(float)(B8*HWp),
                     ws+ST_mdsc, ws+ST_mdbi);
  hipLaunchKernelGGL(k_change, dim3(2048), 256, 0, stream, h2t, ws+OW_mdc2,
                     ws+ST_mdsc, ws+ST_mdbi, ws+OFF_CH);

  // cm chain
  hipLaunchKernelGGL(k_cm1, dim3(512), 256, 0, stream, (const void*)x, dfl, ws+OW_cmw1, t1h);
  hipLaunchKernelGGL(k_cstat, dim3(48*8), 256, 0, stream, (const float*)nullptr, t1h, 1,
                     NC, HW2, B8, 8, ws+ST_t1);
  hipLaunchKernelGGL(k_csb, dim3(1), 64, 0, stream, ws+ST_t1, cmg, cmb, dfl, 1.f/(float)(B8*HW2),
                     ws+ST_cmsc, ws+ST_cmbi);
  hipLaunchKernelGGL(k_cm2, dim3(81,8,3), 256, 0, stream, t1h, ws+ST_cmsc, ws+ST_cmbi,
                     ws+OW_cmct, ws+OFF_T2);
  hipLaunchKernelGGL(k_cm3, dim3(64,8,3), 256, 0, stream, ws+OFF_T2, ws+OW_cmc2, ws+OFF_XM);

  // born + blend
  hipLaunchKernelGGL(k_mom, dim3(128), 256, 0, stream, (const void*)(ws+OFF_XM), (const float*)nullptr, 0,
                     14, B8*HW2, ws+ST_xmm);
  hipLaunchKernelGGL(k_msb, dim3(1), 64, 0, stream, ws+ST_xmm, ws+OW_bow1, bog, bob, dfl,
                     1.f/(float)(B8*HW2), ws+ST_bosc, ws+ST_bobi);
  hipLaunchKernelGGL(k_final, dim3(512), 256, 0, stream, ws+OFF_XM, ws+OFF_CH, ws+OW_bow1,
                     ws+OW_bow2, ws+ST_bosc, ws+ST_bobi, dfl, d_out);
}

// Round 13
// 404.385 us; speedup vs baseline: 1.2115x; 1.1002x over previous
//
#include <hip/hip_runtime.h>
#include <stdint.h>

typedef unsigned short ushort_t;

#define B8  8
#define D6  6
#define NC  48
#define HH  256
#define WW  256
#define HWp 65536
#define H2  128
#define HW2 16384

__device__ __constant__ int c_T0[8] = {0,1,1,1,0,-1,-1,-1};
__device__ __constant__ int c_T1[8] = {1,1,0,-1,-1,-1,0,1};

__device__ inline float bf2f(ushort_t u){ union{unsigned int i; float f;} w; w.i = ((unsigned int)u)<<16; return w.f; }
__device__ inline ushort_t f2bf(float f){ union{float f; unsigned int i;} w; w.f=f; unsigned int xx=w.i;
  return (ushort_t)((xx + 0x7fffu + ((xx>>16)&1u)) >> 16); }
__device__ inline float tanhf_(float x){ float e=__expf(2.f*x); return 1.f - 2.f/(e+1.f); }
__device__ inline float sigm_(float x){ return 1.f/(1.f+__expf(-x)); }
__device__ inline float ldg_(const void* p, size_t i, int isbf){
  return isbf ? bf2f(((const ushort_t*)p)[i]) : ((const float*)p)[i];
}

typedef short short8 __attribute__((ext_vector_type(8)));
typedef float f4 __attribute__((ext_vector_type(4)));
typedef ushort_t us4 __attribute__((ext_vector_type(4)));
typedef ushort_t us8 __attribute__((ext_vector_type(8)));
union AB { short8 s; us4 h[2]; us8 u; };

// BN scale/bias from moment-projection (1x1 conv case): shared helper
__device__ inline void msb_inline(int c, const float* mom, const float* W1,
      const void* g, const void* b, int isbf, float invN, float* sc, float* bi){
  const int st[6]={0,6,11,15,18,20};
  float wr[6];
  #pragma unroll
  for(int d=0;d<6;d++) wr[d]=W1[c*6+d];
  float mean=0.f;
  #pragma unroll
  for(int d=0;d<6;d++) mean += wr[d]*mom[d];
  mean *= invN;
  float e2=0.f;
  #pragma unroll
  for(int d=0;d<6;d++)
    #pragma unroll
    for(int e=d;e<6;e++)
      e2 += wr[d]*wr[e]*((e==d)?1.f:2.f)*mom[6 + st[d] + (e-d)];
  e2 *= invN;
  float var = e2 - mean*mean;
  float s = ldg_(g,c,isbf) * rsqrtf(var + 1e-5f);
  sc[c]=s; bi[c]= ldg_(b,c,isbf) - s*mean;
}

// BN scale/bias from raw sum/sumsq stats
__device__ inline void csb_inline(int c, const float* stats, const void* g, const void* b,
      int isbf, float invN, float* sc, float* bi){
  float mean=stats[2*c]*invN; float var=stats[2*c+1]*invN - mean*mean;
  float s=ldg_(g,c,isbf)*rsqrtf(var+1e-5f);
  sc[c]=s; bi[c]=ldg_(b,c,isbf)-s*mean;
}

// ---------------- detect (+ zero stats region) ----------------
__global__ __launch_bounds__(256) void k_detect(const ushort_t* x, float* stats){
  int t=threadIdx.x;
  for(int i=t;i<1024;i+=256) stats[i]=0.f;
  __syncthreads();
  int cnt=0;
  for(int i=t;i<4096;i+=256){
    ushort_t u=x[2*i];
    int e=(u>>7)&0xff;
    if(e>=100 && e<=150) cnt++;
  }
  for(int o=32;o;o>>=1) cnt+=__shfl_down(cnt,o,64);
  __shared__ int sh4[4];
  if((t&63)==0) sh4[t>>6]=cnt;
  __syncthreads();
  if(t==0){ int tot=sh4[0]+sh4[1]+sh4[2]+sh4[3]; stats[960] = (tot>=2048)?1.f:0.f; }
}

// ---------------- fused prep: wcvt(810) + wprep(21) + mom(x)(256) ----------------
struct WC { const ushort_t* src[10]; int off[10]; int n[10]; };

__global__ __launch_bounds__(256) void k_prep(WC wc, float* dst, const float* dfl,
      const void* mdc1r, const void* mdctr, ushort_t* wb2, ushort_t* wb1,
      const void* x, float* xmom){
  int isbf = dfl[0]>0.5f;
  int bx = blockIdx.x;
  __shared__ float red[4][27];
  if(bx < 810){
    int arr = bx/81, blk = bx-arr*81;
    int n = wc.n[arr]; const ushort_t* s = wc.src[arr]; float* d = dst + wc.off[arr];
    for(int i = blk*256 + threadIdx.x; i < n; i += 81*256)
      d[i] = isbf ? bf2f(s[i]) : ((const float*)s)[i];
  } else if(bx < 831){
    int t = (bx-810)*256+threadIdx.x;
    if(t<3456){
      int lane=t&63; int rest=t>>6;
      int ks=rest&1; int g=rest>>1; int tap=g%9; int nt=g/9;
      int oc=nt*16+(lane&15); int icb=ks*32+((lane>>4)*8);
      #pragma unroll
      for(int j=0;j<8;j++){
        int ic=icb+j;
        float v = (ic<48) ? ldg_(mdc1r,(size_t)(oc*48+ic)*9+tap,isbf) : 0.f;
        wb2[(size_t)t*8+j]=f2bf(v);
      }
    } else if(t<5184){
      int tt=t-3456; int lane=tt&63; int g=tt>>6; int tap=g%9; int nt=g/9;
      int oc=nt*16+(lane&15); int icb=(lane>>4)*8;
      #pragma unroll
      for(int j=0;j<8;j++){
        int ic=icb+j;
        float v = (ic<10) ? ldg_(mdctr,(size_t)(oc*10+ic)*9+tap,isbf) : 0.f;
        wb1[(size_t)tt*8+j]=f2bf(v);
      }
    }
  } else {
    int bm = bx-831;                      // 256 moment blocks
    float vals[27];
    #pragma unroll
    for(int i=0;i<27;i++) vals[i]=0.f;
    for(int p = bm*256+threadIdx.x; p < B8*HWp; p += 256*256){
      int b = p >> 16; int hw = p & 65535;
      float v[6];
      #pragma unroll
      for(int d=0; d<6; d++) v[d]=ldg_(x, (((size_t)(b*6+d))<<16)+hw, isbf);
      int q=6;
      #pragma unroll
      for(int d=0;d<6;d++){
        vals[d]+=v[d];
        #pragma unroll
        for(int e=d;e<6;e++){ vals[q] += v[d]*v[e]; q++; }
      }
    }
    int wid=threadIdx.x>>6, lane=threadIdx.x&63;
    #pragma unroll
    for(int i=0;i<27;i++){
      float v=vals[i];
      for(int o=32;o;o>>=1) v+=__shfl_down(v,o,64);
      if(lane==0) red[wid][i]=v;
    }
    __syncthreads();
    if(threadIdx.x<27)
      atomicAdd(&xmom[threadIdx.x],
        red[0][threadIdx.x]+red[1][threadIdx.x]+red[2][threadIdx.x]+red[3][threadIdx.x]);
  }
}

// ---------------- fused env(2048, inline ce-msb) + cm1(512) ----------------
__global__ __launch_bounds__(256) void k_envcm1(const void* x, const float* dfl,
      const float* xmom, const float* cew1, const float* cew2, const void* ceg, const void* ceb,
      const float* cmw1, float* e, ushort_t* t1){
  int isbf = dfl[0]>0.5f;
  int bx = blockIdx.x;
  __shared__ float sc[48], bi[48];
  if(bx < 2048){
    if(threadIdx.x<48)
      msb_inline(threadIdx.x, xmom, cew1, ceg, ceb, isbf, 1.f/(float)(B8*HWp), sc, bi);
    __syncthreads();
    int p = bx*256+threadIdx.x;
    int b = p >> 16; int hw = p & 65535;
    float v[6];
    #pragma unroll
    for(int d=0; d<6; d++) v[d]=ldg_(x,(size_t)(b*6+d)*HWp + hw, isbf);
    float acc=0.f;
    for(int c=0;c<NC;c++){
      float y=0.f;
      #pragma unroll
      for(int d=0;d<6;d++) y += cew1[c*6+d]*v[d];
      acc += cew2[c]*tanhf_(sc[c]*y + bi[c]);
    }
    e[(size_t)b*HWp + hw]=acc;
  } else {
    int p=(bx-2048)*256+threadIdx.x;
    int b=p>>14; int rem=p&16383; int i=rem>>7; int j=rem&127;
    float v[6][2][2];
    #pragma unroll
    for(int d=0;d<6;d++)
      #pragma unroll
      for(int ki=0;ki<2;ki++)
        #pragma unroll
        for(int kj=0;kj<2;kj++)
          v[d][ki][kj]=ldg_(x, ((size_t)(b*6+d)*HH + 2*i+ki)*WW + 2*j+kj, isbf);
    for(int oc=0;oc<NC;oc++){
      int g=oc>>4;
      float a=0.f;
      #pragma unroll
      for(int icl=0;icl<2;icl++)
        #pragma unroll
        for(int ki=0;ki<2;ki++)
          #pragma unroll
          for(int kj=0;kj<2;kj++)
            a += v[2*g+icl][ki][kj]*cmw1[((oc*2+icl)*2+ki)*2+kj];
      t1[((size_t)(b*NC+oc)*HW2) + rem]=f2bf(a);
    }
  }
}

// ---------------- fused md(2048, r11 config) + cstat(t1)(384) ----------------
__global__ __launch_bounds__(256,3) void k_mdst(const void* x, const float* dfl, const float* e,
      const ushort_t* wb1, const ushort_t* wb2, ushort_t* h2t, float* stats,
      const ushort_t* t1, float* t1stats){
  __shared__ __attribute__((aligned(16))) ushort_t te[6400];    // [pix 20x20][16]
  __shared__ __attribute__((aligned(16))) ushort_t h1t[19488];  // [pix 336][58], 48..55 zero
  __shared__ float red[4][3][16][2];
  int bx = blockIdx.x;
  if(bx >= 2048){
    // ---- cstat role on t1 (bf16), rides in md's shadow ----
    int l = bx-2048;
    int c = l % NC; int s = l / NC;   // 384 blocks: 48ch x 8 splits
    float sum=0.f, sq=0.f;
    for(int b=0;b<B8;b++){
      size_t base=((size_t)b*NC+c)*HW2;
      for(int i=s*256+threadIdx.x; i<HW2; i+=8*256){
        float v = bf2f(t1[base+i]);
        sum+=v; sq+=v*v;
      }
    }
    for(int o=32;o;o>>=1){ sum+=__shfl_down(sum,o,64); sq+=__shfl_down(sq,o,64); }
    int wid=threadIdx.x>>6;
    if((threadIdx.x&63)==0){ red[wid][0][0][0]=sum; red[wid][0][0][1]=sq; }
    __syncthreads();
    if(threadIdx.x==0){
      atomicAdd(&t1stats[2*c],   red[0][0][0][0]+red[1][0][0][0]+red[2][0][0][0]+red[3][0][0][0]);
      atomicAdd(&t1stats[2*c+1], red[0][0][0][1]+red[1][0][0][1]+red[2][0][0][1]+red[3][0][0][1]);
    }
    return;
  }
  int isbf = dfl[0]>0.5f;
  int b = bx>>8; int tile = bx&255;
  int ti = tile>>4, tj = tile&15;
  int i0 = ti*16, j0 = tj*16;
  int lane = threadIdx.x&63, w = threadIdx.x>>6;
  int n = lane&15, quad = lane>>4;
  // phase 0: zero te + h1 ch48..55 tails
  {
    us8 z;
    #pragma unroll
    for(int j=0;j<8;j++) z[j]=0;
    us8* tp=(us8*)te;
    for(int idx=threadIdx.x; idx<800; idx+=256) tp[idx]=z;
    for(int idx=threadIdx.x; idx<336; idx+=256) *(us8*)&h1t[idx*58+48]=z;
  }
  __syncthreads();
  // phase 1: stage te ch0..9
  for(int idx=threadIdx.x; idx<4000; idx+=256){
    int pix = idx/10, ic = idx-pix*10;
    int r = pix/20, c = pix-r*20;
    int gy = i0-2+r, gx = j0-2+c;
    float v = 0.f;
    if(gy>=0 && gy<HH && gx>=0 && gx<WW){
      if(ic<2) v = ldg_(x, ((size_t)(b*6+ic)*HH + gy)*WW + gx, isbf);
      else { int k=ic-2;
        int yy=(gy + c_T1[k]) & 255; int xx=(gx - c_T0[k]) & 255;
        v = e[((size_t)b*HH + yy)*WW + xx]; }
    }
    te[pix*16+ic]=f2bf(v);
  }
  __syncthreads();
  // phase 2: h1 -> h1t[18x18][58]
  {
    int qoff = (quad&1)*8;
    for(int mt=w; mt<21; mt+=4){
      int p = mt*16 + n;
      int pr = p/18, pc = p-pr*18;
      f4 hacc[3];
      #pragma unroll
      for(int nt=0;nt<3;nt++) hacc[nt]=(f4){0.f,0.f,0.f,0.f};
      #pragma unroll
      for(int tap=0; tap<9; tap++){
        int ki=tap/3, kj=tap%3;
        AB a; a.u = *(const us8*)&te[((pr+ki)*20 + pc+kj)*16 + qoff];
        #pragma unroll
        for(int nt=0;nt<3;nt++){
          AB Bf; Bf.u = *(const us8*)&wb1[((size_t)((nt*9+tap)*64+lane))*8];
          hacc[nt] = __builtin_amdgcn_mfma_f32_16x16x32_bf16(a.s, Bf.s, hacc[nt], 0,0,0);
        }
      }
      int pd = mt*16 + quad*4;
      #pragma unroll
      for(int nt=0;nt<3;nt++){
        #pragma unroll
        for(int r=0;r<4;r++)
          h1t[(pd+r)*58 + nt*16 + n] = f2bf(tanhf_(hacc[nt][r]));
      }
    }
  }
  __syncthreads();
  // phase 3: h2 + stats
  f4 acc[4][3];
  #pragma unroll
  for(int a=0;a<4;a++)
    #pragma unroll
    for(int c=0;c<3;c++) acc[a][c]=(f4){0.f,0.f,0.f,0.f};
  int q1off = 32 + ((quad<2) ? quad*8 : 16);
  #pragma unroll
  for(int tap=0; tap<9; tap++){
    int ki=tap/3, kj=tap%3;
    AB Bf[3][2];
    #pragma unroll
    for(int nt=0;nt<3;nt++)
      #pragma unroll
      for(int ks=0;ks<2;ks++)
        Bf[nt][ks].u = *(const us8*)&wb2[((size_t)(((nt*9+tap)*2+ks)*64+lane))*8];
    #pragma unroll
    for(int yy=0; yy<4; yy++){
      int y = w*4 + yy;
      int base = ((y+ki)*18 + n + kj)*58;
      AB a0, a1;
      a0.u = *(const us8*)&h1t[base + quad*8];
      a1.u = *(const us8*)&h1t[base + q1off];
      #pragma unroll
      for(int nt=0;nt<3;nt++){
        acc[yy][nt] = __builtin_amdgcn_mfma_f32_16x16x32_bf16(a0.s, Bf[nt][0].s, acc[yy][nt], 0,0,0);
        acc[yy][nt] = __builtin_amdgcn_mfma_f32_16x16x32_bf16(a1.s, Bf[nt][1].s, acc[yy][nt], 0,0,0);
      }
    }
  }
  float s[3]={0.f,0.f,0.f}, q[3]={0.f,0.f,0.f};
  size_t tilebase = (size_t)bx*48*256;
  #pragma unroll
  for(int yy=0;yy<4;yy++){
    #pragma unroll
    for(int nt=0;nt<3;nt++){
      int oc = nt*16 + n;
      size_t base = tilebase + (size_t)oc*256 + (w*4+yy)*16 + quad*4;
      us4 u;
      #pragma unroll
      for(int r=0;r<4;r++){
        float v=tanhf_(acc[yy][nt][r]);
        u[r]=f2bf(v);
        float vb=bf2f(u[r]);
        s[nt]+=vb; q[nt]+=vb*vb;
      }
      *(us4*)&h2t[base] = u;
    }
  }
  #pragma unroll
  for(int nt=0;nt<3;nt++){
    s[nt]+=__shfl_xor(s[nt],16,64); s[nt]+=__shfl_xor(s[nt],32,64);
    q[nt]+=__shfl_xor(q[nt],16,64); q[nt]+=__shfl_xor(q[nt],32,64);
  }
  if(quad==0){
    #pragma unroll
    for(int nt=0;nt<3;nt++){ red[w][nt][n][0]=s[nt]; red[w][nt][n][1]=q[nt]; }
  }
  __syncthreads();
  if(threadIdx.x<48){
    int oc=threadIdx.x; int nt=oc>>4, nn=oc&15;
    float S=red[0][nt][nn][0]+red[1][nt][nn][0]+red[2][nt][nn][0]+red[3][nt][nn][0];
    float Q=red[0][nt][nn][1]+red[1][nt][nn][1]+red[2][nt][nn][1]+red[3][nt][nn][1];
    atomicAdd(&stats[2*oc],S); atomicAdd(&stats[2*oc+1],Q);
  }
}

// ---------------- fused change(2048, inline md-csb) + cm2(1944, inline cm-csb) ----------------
__global__ __launch_bounds__(256) void k_chcm2(const ushort_t* h2t, const float* dfl,
      const float* mdstats, const void* mdg, const void* mdb, const float* wc2, float* CH,
      const ushort_t* t1, const float* t1stats, const void* cmg, const void* cmb,
      const float* wct, float* t2){
  __shared__ float shbuf[6816];
  int isbf = dfl[0]>0.5f;
  int bx = blockIdx.x;
  if(bx < 2048){
    float* rr = shbuf; float* sc = shbuf+256; float* bi = shbuf+304;
    if(threadIdx.x<48)
      csb_inline(threadIdx.x, mdstats, mdg, mdb, isbf, 1.f/(float)(B8*HWp), sc, bi);
    __syncthreads();
    int tile = bx;
    int b = tile>>8; int rest = tile&255; int ti = rest>>4, tj = rest&15;
    int t = threadIdx.x;
    int pix = t&63, icq = t>>6;
    int oi = pix>>3, oj = pix&7;
    const ushort_t* tp = &h2t[(size_t)tile*48*256];
    float acc = 0.f;
    #pragma unroll
    for(int icl=0; icl<12; icl++){
      int ic = icq*12 + icl;
      float s = sc[ic], tb = bi[ic];
      const ushort_t* cp = tp + ic*256 + (2*oi)*16 + 2*oj;
      acc += tanhf_(s*bf2f(cp[0 ])+tb)*wc2[ic*4+0];
      acc += tanhf_(s*bf2f(cp[1 ])+tb)*wc2[ic*4+1];
      acc += tanhf_(s*bf2f(cp[16])+tb)*wc2[ic*4+2];
      acc += tanhf_(s*bf2f(cp[17])+tb)*wc2[ic*4+3];
    }
    rr[icq*64+pix] = acc;
    __syncthreads();
    if(t<64){
      float v = rr[t]+rr[64+t]+rr[128+t]+rr[192+t];
      int i = ti*8 + (t>>3), j = tj*8 + (t&7);
      CH[((size_t)b<<14) + i*128 + j] = sigm_(v);
    }
  } else {
    float* as = shbuf; float* sc = shbuf+6720; float* bi = shbuf+6768;
    if(threadIdx.x<48)
      csb_inline(threadIdx.x, t1stats, cmg, cmb, isbf, 1.f/(float)(B8*HW2), sc, bi);
    __syncthreads();
    int l = bx-2048;
    int g = l/648; int rem = l-g*648; int b = rem/81; int t = rem-b*81;
    int ti=t/9, tj=t%9;
    int i0=ti*16, j0=tj*16;
    int ty=threadIdx.x>>4, tx=threadIdx.x&15;
    for(int idx=threadIdx.x; idx<6400; idx+=256){
      int i=idx/400; int rm=idx-i*400; int r=rm/20; int cc=rm-r*20;
      int cg=g*16+i;
      int y=i0-2+r, xx=j0-2+cc;
      float v=0.f;
      if(y>=0 && y<H2 && xx>=0 && xx<H2)
        v = tanhf_(sc[cg]*bf2f(t1[((size_t)(b*NC+cg)*H2 + y)*H2 + xx]) + bi[cg]);
      as[(i*20+r)*21+cc]=v;
    }
    __syncthreads();
    float acc[16];
    #pragma unroll
    for(int o=0;o<16;o++) acc[o]=0.f;
    for(int i=0;i<16;i++){
      float p[3][3];
      #pragma unroll
      for(int ki=0;ki<3;ki++)
        #pragma unroll
        for(int kj=0;kj<3;kj++) p[ki][kj]=as[(i*20+ty+ki)*21+tx+kj];
      #pragma unroll
      for(int o=0;o<16;o++){
        const float* wp=&wct[((size_t)(g*16+o)*16+i)*9];
        float a=0.f;
        #pragma unroll
        for(int q=0;q<9;q++) a += p[q/3][q%3]*wp[q];
        acc[o]+=a;
      }
    }
    int ii=i0+ty, jj=j0+tx;
    if(ii<130 && jj<130){
      #pragma unroll
      for(int o=0;o<16;o++)
        t2[((size_t)(b*NC+g*16+o)*130 + ii)*130 + jj]=tanhf_(acc[o]);
    }
  }
}

// ---------------- xm: group in z ----------------
__global__ __launch_bounds__(256) void k_cm3(const float* t2, const float* w, float* xm){
  __shared__ float ts[16][18][20];
  int b=blockIdx.y, g=blockIdx.z;
  int ti=blockIdx.x>>3, tj=blockIdx.x&7;
  int i0=ti*16, j0=tj*16;
  int ty=threadIdx.x>>4, tx=threadIdx.x&15;
  for(int idx=threadIdx.x; idx<16*18*18; idx+=256){
    int i=idx/324; int rem=idx-i*324; int r=rem/18; int cc=rem-r*18;
    int cg=g*16+i;
    ts[i][r][cc]=t2[((size_t)(b*NC+cg)*130 + i0+r)*130 + j0+cc];
  }
  __syncthreads();
  float acc[2]={0.f,0.f};
  for(int icl=0;icl<16;icl++){
    float p[3][3];
    #pragma unroll
    for(int ki=0;ki<3;ki++)
      #pragma unroll
      for(int kj=0;kj<3;kj++) p[ki][kj]=ts[icl][ty+ki][tx+kj];
    #pragma unroll
    for(int ol=0;ol<2;ol++){
      int oc=2*g+ol;
      const float* wp=&w[((size_t)oc*16+icl)*9];
      float a=0.f;
      #pragma unroll
      for(int q=0;q<9;q++) a += p[q/3][q%3]*wp[q];
      acc[ol]+=a;
    }
  }
  int ii=i0+ty, jj=j0+tx;
  #pragma unroll
  for(int ol=0;ol<2;ol++)
    xm[((size_t)(b*6+2*g+ol)*H2 + ii)*H2 + jj]=tanhf_(acc[ol]);
}

// ---------------- moments of xm (for bo BN) ----------------
__global__ __launch_bounds__(256) void k_mom(const float* src, float* out){
  float vals[27];
  #pragma unroll
  for(int i=0;i<27;i++) vals[i]=0.f;
  int stride = gridDim.x*256;
  for(int p = blockIdx.x*256+threadIdx.x; p < B8*HW2; p += stride){
    int b = p >> 14; int hw = p & 16383;
    float v[6];
    #pragma unroll
    for(int d=0; d<6; d++) v[d]=src[(((size_t)(b*6+d))<<14)+hw];
    int q=6;
    #pragma unroll
    for(int d=0;d<6;d++){
      vals[d]+=v[d];
      #pragma unroll
      for(int e=d;e<6;e++){ vals[q] += v[d]*v[e]; q++; }
    }
  }
  __shared__ float red[4][27];
  int wid=threadIdx.x>>6, lane=threadIdx.x&63;
  #pragma unroll
  for(int i=0;i<27;i++){
    float v=vals[i];
    for(int o=32;o;o>>=1) v+=__shfl_down(v,o,64);
    if(lane==0) red[wid][i]=v;
  }
  __syncthreads();
  if(threadIdx.x<27)
    atomicAdd(&out[threadIdx.x],
      red[0][threadIdx.x]+red[1][threadIdx.x]+red[2][threadIdx.x]+red[3][threadIdx.x]);
}

// ---------------- final (inline bo-msb) ----------------
__global__ __launch_bounds__(256) void k_final(const float* xm, const float* CH,
      const float* xmmom, const float* w1, const float* w2, const void* bog, const void* bob,
      const float* dfl, void* outp){
  int isbf = dfl[0]>0.5f;
  __shared__ float sc[48], bi[48];
  if(threadIdx.x<48)
    msb_inline(threadIdx.x, xmmom, w1, bog, bob, isbf, 1.f/(float)(B8*HW2), sc, bi);
  __syncthreads();
  int p=blockIdx.x*256+threadIdx.x;
  int b=p>>14; int rem=p&16383;
  float v[6];
  #pragma unroll
  for(int d=0;d<6;d++) v[d]=xm[((size_t)(b*6+d)*HW2)+rem];
  float born[6]={0.f,0.f,0.f,0.f,0.f,0.f};
  for(int c=0;c<NC;c++){
    float y=0.f;
    #pragma unroll
    for(int d=0;d<6;d++) y+=w1[c*6+d]*v[d];
    float a=tanhf_(sc[c]*y+bi[c]);
    #pragma unroll
    for(int d=0;d<6;d++) born[d]+=w2[d*NC+c]*a;
  }
  float C=CH[p];
  #pragma unroll
  for(int d=0;d<6;d++){
    float o=v[d]*(1.f-C)+C*born[d];
    if(d<3) o=sigm_(o);
    size_t id=((size_t)(b*6+d)*HW2)+rem;
    if(isbf) ((ushort_t*)outp)[id]=f2bf(o); else ((float*)outp)[id]=o;
  }
}

extern "C" void kernel_launch(void* const* d_in, const int* in_sizes, int n_in,
                              void* d_out, int out_size, void* d_ws, size_t ws_size,
                              hipStream_t stream){
  (void)in_sizes; (void)n_in; (void)out_size; (void)ws_size;
  const ushort_t* x    = (const ushort_t*)d_in[0];
  const ushort_t* cew1 = (const ushort_t*)d_in[1];
  const void*     ceg  = d_in[2];
  const void*     ceb  = d_in[3];
  const ushort_t* cew2 = (const ushort_t*)d_in[4];
  const ushort_t* mdct = (const ushort_t*)d_in[5];
  const ushort_t* mdc1 = (const ushort_t*)d_in[6];
  const void*     mdg  = d_in[7];
  const void*     mdb  = d_in[8];
  const ushort_t* mdc2 = (const ushort_t*)d_in[9];
  const ushort_t* cmw1 = (const ushort_t*)d_in[10];
  const void*     cmg  = d_in[11];
  const void*     cmb  = d_in[12];
  const ushort_t* cmct = (const ushort_t*)d_in[13];
  const ushort_t* cmc2 = (const ushort_t*)d_in[14];
  const ushort_t* bow1 = (const ushort_t*)d_in[15];
  const void*     bog  = d_in[16];
  const void*     bob  = d_in[17];
  const ushort_t* bow2 = (const ushort_t*)d_in[18];
  float* ws = (float*)d_ws;

  const long OW_mdct=0, OW_mdc1=4320, OW_cew1=25056, OW_cew2=25344, OW_mdc2=25392,
             OW_cmw1=25584, OW_cmct=25968, OW_cmc2=32880, OW_bow1=33744, OW_bow2=34032;
  const long OFF_STATS=34320;
  const long ST_xmom=OFF_STATS+0,
             ST_h2  =OFF_STATS+160,
             ST_t1  =OFF_STATS+352,
             ST_xmm =OFF_STATS+544;
  const long OFF_WB2 = OFF_STATS + 1024;
  const long OFF_WB1 = OFF_WB2 + 13824;
  const long OFF_E   = OFF_WB1 + 6912;
  const long OFF_H2  = OFF_E + 524288L;
  const long OFF_D   = OFF_H2 + 12582912L;
  const long OFF_T1=OFF_D, OFF_T2=OFF_D+6291456L, OFF_XM=OFF_D+12781056L, OFF_CH=OFF_D+13567488L;

  ushort_t* h2t  = (ushort_t*)(ws + OFF_H2);
  ushort_t* t1h  = (ushort_t*)(ws + OFF_T1);
  ushort_t* wb2  = (ushort_t*)(ws + OFF_WB2);
  ushort_t* wb1  = (ushort_t*)(ws + OFF_WB1);
  const float* dfl = ws + OFF_STATS + 960;

  // 1: zero stats + dtype flag
  hipLaunchKernelGGL(k_detect, dim3(1), 256, 0, stream, x, ws+OFF_STATS);

  // 2: wcvt + wprep + mom(x)
  WC wc;
  const ushort_t* srcs[10] = {mdct,mdc1,cew1,cew2,mdc2,cmw1,cmct,cmc2,bow1,bow2};
  const int offs[10] = {(int)OW_mdct,(int)OW_mdc1,(int)OW_cew1,(int)OW_cew2,(int)OW_mdc2,
                        (int)OW_cmw1,(int)OW_cmct,(int)OW_cmc2,(int)OW_bow1,(int)OW_bow2};
  const int cnts[10] = {4320,20736,288,48,192,384,6912,864,288,288};
  for(int i=0;i<10;i++){ wc.src[i]=srcs[i]; wc.off[i]=offs[i]; wc.n[i]=cnts[i]; }
  hipLaunchKernelGGL(k_prep, dim3(1087), 256, 0, stream, wc, ws, dfl,
                     (const void*)mdc1, (const void*)mdct, wb2, wb1, (const void*)x, ws+ST_xmom);

  // 3: env (inline ce-msb) + cm1
  hipLaunchKernelGGL(k_envcm1, dim3(2560), 256, 0, stream, (const void*)x, dfl,
                     ws+ST_xmom, ws+OW_cew1, ws+OW_cew2, ceg, ceb, ws+OW_cmw1,
                     ws+OFF_E, t1h);

  // 4: fused md (h1 LDS-resident) + h2 stats + cstat(t1) riding along
  hipLaunchKernelGGL(k_mdst, dim3(2432), 256, 0, stream, (const void*)x, dfl, ws+OFF_E,
                     wb1, wb2, h2t, ws+ST_h2, t1h, ws+ST_t1);

  // 5: change (inline md-csb) + cm2 (inline cm-csb)
  hipLaunchKernelGGL(k_chcm2, dim3(3992), 256, 0, stream, h2t, dfl,
                     ws+ST_h2, mdg, mdb, ws+OW_mdc2, ws+OFF_CH,
                     t1h, ws+ST_t1, cmg, cmb, ws+OW_cmct, ws+OFF_T2);

  // 6: cm3
  hipLaunchKernelGGL(k_cm3, dim3(64,8,3), 256, 0, stream, ws+OFF_T2, ws+OW_cmc2, ws+OFF_XM);

  // 7: moments of xm
  hipLaunchKernelGGL(k_mom, dim3(128), 256, 0, stream, ws+OFF_XM, ws+ST_xmm);

  // 8: final (inline bo-msb)
  hipLaunchKernelGGL(k_final, dim3(512), 256, 0, stream, ws+OFF_XM, ws+OFF_CH,
                     ws+ST_xmm, ws+OW_bow1, ws+OW_bow2, bog, bob, dfl, d_out);
}